// Round 11
// baseline (2031.902 us; speedup 1.0000x reference)
//
#include <hip/hip_runtime.h>

#define C0n 50000
#define C1n 150000
#define C2n 300000
#define E0n 300000
#define E1n 600000
#define NEn (E0n + E1n)
#define BWD 256
#define NB1 ((C1n + BWD - 1) / BWD)   // 586
#define NB2 ((C0n + BWD - 1) / BWD)   // 196

typedef float  v4f    __attribute__((ext_vector_type(4)));
typedef float  v2f    __attribute__((ext_vector_type(2)));
typedef float  f32x4  __attribute__((ext_vector_type(4)));
typedef short  bf16x8 __attribute__((ext_vector_type(8)));
typedef unsigned short u16;
typedef unsigned long long u64;

__device__ __forceinline__ u16 f2bf(float f){
    unsigned u = __builtin_bit_cast(unsigned, f);
    u += 0x7FFFu + ((u >> 16) & 1u);          // RNE
    return (u16)(u >> 16);
}
__device__ __forceinline__ float bf2f(u16 h){
    unsigned u = ((unsigned)h) << 16;
    return __builtin_bit_cast(float, u);
}
__device__ __forceinline__ f32x4 mfma16(bf16x8 a, bf16x8 b, f32x4 c){
    return __builtin_amdgcn_mfma_f32_16x16x32_bf16(a, b, c, 0, 0, 0);
}
__device__ __forceinline__ float red16(float v){
    v += __shfl_xor(v, 1); v += __shfl_xor(v, 2);
    v += __shfl_xor(v, 4); v += __shfl_xor(v, 8);
    return v;
}
// 8 consecutive f32 -> bf16x8 fragment (16B-aligned source)
__device__ __forceinline__ bf16x8 frag8(const float* __restrict__ p){
    v4f a = *(const v4f*)p, b = *(const v4f*)(p + 4);
    bf16x8 r;
    r[0] = (short)f2bf(a[0]); r[1] = (short)f2bf(a[1]);
    r[2] = (short)f2bf(a[2]); r[3] = (short)f2bf(a[3]);
    r[4] = (short)f2bf(b[0]); r[5] = (short)f2bf(b[1]);
    r[6] = (short)f2bf(b[2]); r[7] = (short)f2bf(b[3]);
    return r;
}

// ------- xp_t = relu(x @ Wp[t] + bp[t]) for ALL t (r8-validated, guarded tiles) -------
__global__ __launch_bounds__(256) void k_projm3(const float* __restrict__ x,
    const float* __restrict__ Wp, const float* __restrict__ bp,
    u16* __restrict__ xp3)
{
    __shared__ u16 Wt[3][64 * 72];   // [t][c][k], pad to 72
    __shared__ float bps[3 * 64];
    const int tid = threadIdx.x;
    for (int i = tid; i < 192; i += 256) bps[i] = bp[i];
    for (int t = 0; t < 3; t++)
        for (int idx = tid; idx < 64 * 64; idx += 256) {
            int k = idx >> 6, c = idx & 63;      // idx = k*64 + c
            Wt[t][c * 72 + k] = f2bf(Wp[t * 4096 + idx]);
        }
    __syncthreads();

    const int lane = tid & 63, wid = tid >> 6;
    const int lr = lane & 15, lg = lane >> 4;
    const int ntiles = C2n / 16;                  // 18750
    int rt = blockIdx.x * 4 + wid;
    const bool valid = (rt < ntiles);
    if (rt > ntiles - 1) rt = ntiles - 1;         // clamp for loads only
    const int r0 = rt * 16;

    // x fragments: t-invariant, load once
    bf16x8 xa[2];
    xa[0] = frag8(&x[(size_t)(r0 + lr) * 64 + 0  + 8 * lg]);
    xa[1] = frag8(&x[(size_t)(r0 + lr) * 64 + 32 + 8 * lg]);

    for (int t = 0; t < 3; t++) {
        f32x4 acc[4];
#pragma unroll
        for (int n = 0; n < 4; n++) acc[n] = 0;
#pragma unroll
        for (int ks = 0; ks < 2; ks++) {
#pragma unroll
            for (int n = 0; n < 4; n++) {
                bf16x8 b = *(const bf16x8*)&Wt[t][(16 * n + lr) * 72 + ks * 32 + 8 * lg];
                acc[n] = mfma16(xa[ks], b, acc[n]);
            }
        }
        if (valid) {
            u16* xp = xp3 + (size_t)t * C2n * 64;
#pragma unroll
            for (int n = 0; n < 4; n++) {
                const float bb = bps[t * 64 + 16 * n + lr];
#pragma unroll
                for (int j = 0; j < 4; j++)
                    xp[(size_t)(r0 + 4 * lg + j) * 64 + 16 * n + lr] =
                        f2bf(fmaxf(acc[n][j] + bb, 0.f));
            }
        }
    }
}

// ---------------- CSR build: histogram ----------------
__global__ __launch_bounds__(256) void k_hist(const int* __restrict__ d0,
    const int* __restrict__ d1, const int* __restrict__ d2,
    int* __restrict__ deg, int nE, int nV)
{
    const int e = blockIdx.x * 256 + threadIdx.x;
    if (e >= nE) return;
    const int y = blockIdx.y;
    const int* d = (y == 0) ? d0 : (y == 1) ? d1 : d2;
    atomicAdd(&deg[(size_t)y * nV + d[e]], 1);
}

// ---------------- CSR build: exclusive scan ----------------
__global__ __launch_bounds__(256) void k_scan_a(int* __restrict__ a, int n,
    int* __restrict__ bsum, int nblk)
{
    __shared__ int sd[256];
    const int t = threadIdx.x, y = blockIdx.y;
    int* arr = a + (size_t)y * n;
    const int base = blockIdx.x * 2048 + t * 8;
    int v[8];
#pragma unroll
    for (int j = 0; j < 8; j++) v[j] = (base + j < n) ? arr[base + j] : 0;
    int tot = 0;
#pragma unroll
    for (int j = 0; j < 8; j++) { int tmp = v[j]; v[j] = tot; tot += tmp; }
    sd[t] = tot; __syncthreads();
    for (int off = 1; off < 256; off <<= 1) {
        int xv = (t >= off) ? sd[t - off] : 0;
        __syncthreads();
        sd[t] += xv;
        __syncthreads();
    }
    const int excl = sd[t] - tot;
#pragma unroll
    for (int j = 0; j < 8; j++)
        if (base + j < n) arr[base + j] = excl + v[j];
    if (t == 255) bsum[y * nblk + blockIdx.x] = sd[255];
}

__global__ __launch_bounds__(256) void k_scan_b(int* __restrict__ bsum, int nblk)
{
    __shared__ int sd[256];
    const int t = threadIdx.x, y = blockIdx.y;
    int val = (t < nblk) ? bsum[y * nblk + t] : 0;
    sd[t] = val; __syncthreads();
    for (int off = 1; off < 256; off <<= 1) {
        int xv = (t >= off) ? sd[t - off] : 0;
        __syncthreads();
        sd[t] += xv;
        __syncthreads();
    }
    if (t < nblk) bsum[y * nblk + t] = sd[t] - val;
}

__global__ __launch_bounds__(256) void k_scan_c(int* __restrict__ a, int n,
    const int* __restrict__ bsum, int nblk)
{
    const int t = threadIdx.x, y = blockIdx.y;
    int* arr = a + (size_t)y * n;
    const int base = blockIdx.x * 2048 + t * 8;
    const int add = bsum[y * nblk + blockIdx.x];
#pragma unroll
    for (int j = 0; j < 8; j++)
        if (base + j < n) arr[base + j] += add;
}

// -------- bucketed fill pass 1: append (src,dst) records into per-bucket segments --------
// bucket b = dst >> 8; segment base = rp[b*BWD] (from the existing scan). Appends are
// dense within each segment -> cacheline-friendly writes.
__global__ __launch_bounds__(256) void k_bfill1(const int* __restrict__ s0,
    const int* __restrict__ s1, const int* __restrict__ s2,
    const int* __restrict__ d0, const int* __restrict__ d1, const int* __restrict__ d2,
    const int* __restrict__ rp, int* __restrict__ cnt,
    u64* __restrict__ ebuf, int nE, int nV, int nbkt)
{
    const int e = blockIdx.x * 256 + threadIdx.x;
    if (e >= nE) return;
    const int y = blockIdx.y;
    const int* s = (y == 0) ? s0 : (y == 1) ? s1 : s2;
    const int* d = (y == 0) ? d0 : (y == 1) ? d1 : d2;
    const int dd = d[e];
    const int b = dd >> 8;                       // BWD = 256
    const int base = rp[(size_t)y * nV + b * BWD];
    const int pos = base + atomicAdd(&cnt[y * nbkt + b], 1);
    ebuf[(size_t)y * nE + pos] = (u64)(unsigned)s[e] | ((u64)(unsigned)dd << 32);
}

// -------- bucketed fill pass 2: per-bucket local scatter to final CSR positions --------
// Each dst lives in exactly one bucket -> no cross-block races on fill[]. el writes land
// in the bucket's ~6KB window (L2-resident).
__global__ __launch_bounds__(256) void k_bfill2(const int* __restrict__ rp,
    int* __restrict__ fill, const u64* __restrict__ ebuf,
    int* __restrict__ el, int nE, int nV, int nbkt)
{
    const int b = blockIdx.x, y = blockIdx.y;
    const int lo = rp[(size_t)y * nV + b * BWD];
    const int bhi = (b + 1) * BWD;
    const int hi = (bhi >= nV) ? nE : rp[(size_t)y * nV + bhi];
    for (int i = lo + threadIdx.x; i < hi; i += 256) {
        const u64 rec = ebuf[(size_t)y * nE + i];
        const int s  = (int)(unsigned)(rec & 0xffffffffull);
        const int dd = (int)(unsigned)(rec >> 32);
        const int pos = rp[(size_t)y * nV + dd] + atomicAdd(&fill[(size_t)y * nV + dd], 1);
        el[(size_t)y * nE + pos] = s;
    }
}

// ---------------- gather layer1: agg_t[r] = mean of xp_t[src] (bf16 -> bf16) ----------------
__global__ __launch_bounds__(256) void k_gath1(const int* __restrict__ rp,
    const int* __restrict__ el, const u16* __restrict__ xp,
    u16* __restrict__ aggt)
{
    const int gid = blockIdx.x * 4 + (threadIdx.x >> 6);
    if (gid >= C1n) return;
    const int lane = threadIdx.x & 63;
    const int b = rp[gid];
    const int e = (gid == C1n - 1) ? NEn : rp[gid + 1];
    float s = 0.f;
    for (int i = b; i < e; i++) {
        const int sr = el[i];
        s += bf2f(xp[(size_t)sr * 64 + lane]);
    }
    const float inv = 1.f / (float)max(e - b, 1);
    aggt[(size_t)gid * 64 + lane] = f2bf(s * inv);
}

// ------- fused layer1 (r8-validated): per-t staging, 256 thr, valid-guard;
//         h1 = LN(relu(sum/3)) written ONCE as bf16 -------
__global__ __launch_bounds__(256) void k_out1f(const u16* __restrict__ agg3,
    const float* __restrict__ x,
    const float* __restrict__ Wl, const float* __restrict__ Wr,
    const float* __restrict__ bl,
    const float* __restrict__ g0, const float* __restrict__ b0,
    u16* __restrict__ h1)
{
    __shared__ u16 Wt[128 * 136];   // [c][k], pad to 136
    __shared__ float bls[3 * 128], gs[128], bs[128];
    const int tid = threadIdx.x;
    if (tid < 128) { gs[tid] = g0[tid]; bs[tid] = b0[tid]; }
    for (int i = tid; i < 384; i += 256) bls[i] = bl[i];

    const int lane = tid & 63, wid = tid >> 6;
    const int lr = lane & 15, lg = lane >> 4;
    const int ntiles = C1n / 16;                  // 9375
    int rt = blockIdx.x * 4 + wid;
    const bool valid = (rt < ntiles);
    if (rt > ntiles - 1) rt = ntiles - 1;         // clamp for loads only
    const int r0 = rt * 16;

    // x fragments: t-invariant, load once
    bf16x8 xa[2];
    xa[0] = frag8(&x[(size_t)(r0 + lr) * 64 + 0  + 8 * lg]);
    xa[1] = frag8(&x[(size_t)(r0 + lr) * 64 + 32 + 8 * lg]);

    f32x4 hacc[8];
#pragma unroll
    for (int n = 0; n < 8; n++) hacc[n] = 0;

    for (int t = 0; t < 3; t++) {
        __syncthreads();                          // Wt reuse protection
        const float* WlT = Wl + (size_t)t * 64 * 128;
        const float* WrT = Wr + (size_t)t * 64 * 128;
        for (int idx = tid; idx < 128 * 128; idx += 256) {
            int k = idx >> 7, c = idx & 127;
            float w = (k < 64) ? WlT[k * 128 + c] : WrT[(k - 64) * 128 + c];
            Wt[c * 136 + k] = f2bf(w);
        }
        __syncthreads();

        const u16* aggT = agg3 + (size_t)t * C1n * 64;
        f32x4 ta[8];
#pragma unroll
        for (int n = 0; n < 8; n++) ta[n] = 0;
#pragma unroll
        for (int ks = 0; ks < 4; ks++) {
            bf16x8 a;
            if (ks < 2)
                a = *(const bf16x8*)&aggT[(size_t)(r0 + lr) * 64 + ks * 32 + 8 * lg];
            else
                a = xa[ks - 2];
#pragma unroll
            for (int n = 0; n < 8; n++) {
                bf16x8 b = *(const bf16x8*)&Wt[(16 * n + lr) * 136 + ks * 32 + 8 * lg];
                ta[n] = mfma16(a, b, ta[n]);
            }
        }
        // + bias, row L2 norm (row = 4*lg + j; cols spread over 16 lanes x 8 n-tiles)
        float ss[4] = {0.f, 0.f, 0.f, 0.f};
#pragma unroll
        for (int n = 0; n < 8; n++) {
            const float bb = bls[t * 128 + 16 * n + lr];
#pragma unroll
            for (int j = 0; j < 4; j++) {
                ta[n][j] += bb;
                ss[j] += ta[n][j] * ta[n][j];
            }
        }
#pragma unroll
        for (int j = 0; j < 4; j++)
            ss[j] = 1.f / fmaxf(sqrtf(red16(ss[j])), 1e-12f);
#pragma unroll
        for (int n = 0; n < 8; n++)
#pragma unroll
            for (int j = 0; j < 4; j++) hacc[n][j] += ta[n][j] * ss[j];
    }

    // relu + /3 + LayerNorm over 128 cols
    float mu[4] = {0.f, 0.f, 0.f, 0.f};
#pragma unroll
    for (int n = 0; n < 8; n++)
#pragma unroll
        for (int j = 0; j < 4; j++) {
            float v = fmaxf(hacc[n][j], 0.f) * (1.f / 3.f);
            hacc[n][j] = v; mu[j] += v;
        }
#pragma unroll
    for (int j = 0; j < 4; j++) mu[j] = red16(mu[j]) * (1.f / 128.f);
    float var[4] = {0.f, 0.f, 0.f, 0.f};
#pragma unroll
    for (int n = 0; n < 8; n++)
#pragma unroll
        for (int j = 0; j < 4; j++) {
            float d = hacc[n][j] - mu[j]; var[j] += d * d;
        }
#pragma unroll
    for (int j = 0; j < 4; j++) var[j] = rsqrtf(red16(var[j]) * (1.f / 128.f) + 1e-5f);

    if (valid) {
#pragma unroll
        for (int n = 0; n < 8; n++) {
            const float g = gs[16 * n + lr], bb = bs[16 * n + lr];
#pragma unroll
            for (int j = 0; j < 4; j++) {
                float o = (hacc[n][j] - mu[j]) * var[j] * g + bb;
                h1[(size_t)(r0 + 4 * lg + j) * 128 + 16 * n + lr] = f2bf(o);
            }
        }
    }
}

// ---------------- gather layer2: agg2_t[r] = mean of h1[src] (bf16 -> bf16) ----------------
__global__ __launch_bounds__(256) void k_gath2(const int* __restrict__ rp,
    const int* __restrict__ el, const u16* __restrict__ h1,
    u16* __restrict__ agg2t)
{
    const int gid = blockIdx.x * 4 + (threadIdx.x >> 6);
    if (gid >= C0n) return;
    const int lane = threadIdx.x & 63;
    const int b = rp[gid];
    const int e = (gid == C0n - 1) ? E0n : rp[gid + 1];
    float s0 = 0.f, s1 = 0.f;
    for (int i = b; i < e; i++) {
        const int sr = el[i];
        unsigned u = *(const unsigned*)&h1[(size_t)sr * 128 + lane * 2];
        s0 += bf2f((u16)(u & 0xffffu));
        s1 += bf2f((u16)(u >> 16));
    }
    const float inv = 1.f / (float)max(e - b, 1);
    unsigned o = (unsigned)f2bf(s0 * inv) | ((unsigned)f2bf(s1 * inv) << 16);
    *(unsigned*)&agg2t[(size_t)gid * 128 + lane * 2] = o;
}

// ------- fused layer2 (r8-validated): per-t/hh staging, 256 thr, valid-guard -------
__global__ __launch_bounds__(256) void k_out2f(const u16* __restrict__ agg2,
    const u16* __restrict__ h1,
    const float* __restrict__ Wl2, const float* __restrict__ Wr2,
    const float* __restrict__ bl2,
    const float* __restrict__ g1, const float* __restrict__ b1,
    float* __restrict__ out)
{
    __shared__ u16 Wt[128 * 136];
    __shared__ float bsm[128], gs[128], bs[128];
    const int tid = threadIdx.x;
    if (tid < 128) {
        gs[tid] = g1[tid]; bs[tid] = b1[tid];
        bsm[tid] = bl2[tid] + bl2[128 + tid] + bl2[256 + tid];
    }
    const int lane = tid & 63, wid = tid >> 6;
    const int lr = lane & 15, lg = lane >> 4;
    const int ntiles = C0n / 16;                  // 3125
    int rt = blockIdx.x * 4 + wid;
    const bool valid = (rt < ntiles);
    if (rt > ntiles - 1) rt = ntiles - 1;         // clamp for loads only
    const int r0 = rt * 16;

    // h1 fragments: t-invariant, load once (bf16 direct)
    bf16x8 ha[4];
#pragma unroll
    for (int ks = 0; ks < 4; ks++)
        ha[ks] = *(const bf16x8*)&h1[(size_t)(r0 + lr) * 128 + ks * 32 + 8 * lg];

    f32x4 acc[8];
#pragma unroll
    for (int n = 0; n < 8; n++) acc[n] = 0;

    for (int t = 0; t < 3; t++) {
        for (int hh = 0; hh < 2; hh++) {
            __syncthreads();                      // Wt reuse protection
            const float* W = hh ? Wr2 + (size_t)t * 128 * 128
                                : Wl2 + (size_t)t * 128 * 128;
            for (int idx = tid; idx < 128 * 128; idx += 256) {
                int k = idx >> 7, c = idx & 127;
                Wt[c * 136 + k] = f2bf(W[idx]);   // idx = k*128 + c
            }
            __syncthreads();
#pragma unroll
            for (int ks = 0; ks < 4; ks++) {
                bf16x8 a;
                if (hh == 0)
                    a = *(const bf16x8*)&agg2[(size_t)t * C0n * 128 +
                                              (size_t)(r0 + lr) * 128 + ks * 32 + 8 * lg];
                else
                    a = ha[ks];
#pragma unroll
                for (int n = 0; n < 8; n++) {
                    bf16x8 b = *(const bf16x8*)&Wt[(16 * n + lr) * 136 + ks * 32 + 8 * lg];
                    acc[n] = mfma16(a, b, acc[n]);
                }
            }
        }
    }

    // (acc + Σbias)/3, relu, LN
    float mu[4] = {0.f, 0.f, 0.f, 0.f};
#pragma unroll
    for (int n = 0; n < 8; n++) {
        const float bb = bsm[16 * n + lr];
#pragma unroll
        for (int j = 0; j < 4; j++) {
            float v = fmaxf((acc[n][j] + bb) * (1.f / 3.f), 0.f);
            acc[n][j] = v; mu[j] += v;
        }
    }
#pragma unroll
    for (int j = 0; j < 4; j++) mu[j] = red16(mu[j]) * (1.f / 128.f);
    float var[4] = {0.f, 0.f, 0.f, 0.f};
#pragma unroll
    for (int n = 0; n < 8; n++)
#pragma unroll
        for (int j = 0; j < 4; j++) {
            float d = acc[n][j] - mu[j]; var[j] += d * d;
        }
#pragma unroll
    for (int j = 0; j < 4; j++) var[j] = rsqrtf(red16(var[j]) * (1.f / 128.f) + 1e-5f);

    if (valid) {
#pragma unroll
        for (int n = 0; n < 8; n++) {
            const float g = gs[16 * n + lr], bb = bs[16 * n + lr];
#pragma unroll
            for (int j = 0; j < 4; j++) {
                float o = (acc[n][j] - mu[j]) * var[j] * g + bb;
                out[(size_t)(r0 + 4 * lg + j) * 128 + 16 * n + lr] = o;
            }
        }
    }
}

extern "C" void kernel_launch(void* const* d_in, const int* in_sizes, int n_in,
                              void* d_out, int out_size, void* d_ws, size_t ws_size,
                              hipStream_t stream)
{
    const float* x   = (const float*)d_in[0];
    const int*   ei[3] = { (const int*)d_in[1], (const int*)d_in[2], (const int*)d_in[3] };
    const float* Wp  = (const float*)d_in[6];
    const float* bp  = (const float*)d_in[7];
    const float* Wl  = (const float*)d_in[8];
    const float* bl  = (const float*)d_in[9];
    const float* Wr  = (const float*)d_in[10];
    const float* Wl2 = (const float*)d_in[11];
    const float* bl2 = (const float*)d_in[12];
    const float* Wr2 = (const float*)d_in[13];
    const float* g0  = (const float*)d_in[14];
    const float* b0  = (const float*)d_in[15];
    const float* g1  = (const float*)d_in[16];
    const float* b1  = (const float*)d_in[17];

    // ---- workspace layout (bytes) ----
    char* W = (char*)d_ws;
    u16*   agg3 = (u16*)(W + 0);             // 3*C1*64 bf16 = 57,600,000
    u16*   xp3  = (u16*)(W + 57600000);      // 3*C2*64 bf16 = 115,200,000 -> 172,800,000
    u16*   h1   = (u16*)(W + 57600000);      // C1*128 bf16 = 38,400,000 (overlays xp3 t=0)
    int*   rp1  = (int*)(W + 172800000);     // 3*C1*4 = 1,800,000
    int*   fill1= (int*)(W + 174600000);     // 1,800,000
    int*   bsum = (int*)(W + 176400000);     // 4 KiB
    int*   el1  = (int*)(W + 176404096);     // 3*NE*4 = 10,800,000 -> ends 187,204,096
    // CSR-phase overlays (dead regions during the build):
    int*   cnt1 = (int*)(W + 0);             // 3*NB1 ints (agg3 region, written later by gath1)
    u64*   ebuf1= (u64*)(W + 57600000);      // 3*NEn*8 = 21.6MB (xp3 region, written later by projm3)
    // layer-2 overlays: agg3 dead after out1f
    u16*   agg2 = (u16*)(W + 0);             // 3*C0*128 bf16 = 38,400,000
    int*   rp2  = (int*)(W + 38400000);      // 600,000
    int*   fill2= (int*)(W + 39000000);      // 600,000
    int*   el2  = (int*)(W + 39600000);      // 3*E0*4 = 3,600,000 -> ends 43,200,000
    int*   cnt2 = (int*)(W + 0);             // 3*NB2 ints (agg2 region, written later by gath2)
    u64*   ebuf2= (u64*)(W + 96000000);      // 3*E0*8 = 7.2MB (xp3 t1/t2 region, dead after gath1)

    const int nb1 = (C1n + 2047) / 2048;  // 74
    const int nb2 = (C0n + 2047) / 2048;  // 25

    // ---- CSR layer 1 (dst over full edge list, nV=C1) ----
    hipMemsetAsync(rp1, 0, 2 * 3 * (size_t)C1n * 4, stream);   // rp1 + fill1
    hipMemsetAsync(cnt1, 0, 3 * (size_t)NB1 * 4, stream);
    k_hist<<<dim3((NEn + 255) / 256, 3), 256, 0, stream>>>(
        ei[0] + NEn, ei[1] + NEn, ei[2] + NEn, rp1, NEn, C1n);
    k_scan_a<<<dim3(nb1, 3), 256, 0, stream>>>(rp1, C1n, bsum, nb1);
    k_scan_b<<<dim3(1, 3), 256, 0, stream>>>(bsum, nb1);
    k_scan_c<<<dim3(nb1, 3), 256, 0, stream>>>(rp1, C1n, bsum, nb1);
    k_bfill1<<<dim3((NEn + 255) / 256, 3), 256, 0, stream>>>(
        ei[0], ei[1], ei[2], ei[0] + NEn, ei[1] + NEn, ei[2] + NEn,
        rp1, cnt1, ebuf1, NEn, C1n, NB1);
    k_bfill2<<<dim3(NB1, 3), 256, 0, stream>>>(rp1, fill1, ebuf1, el1, NEn, C1n, NB1);

    // ---- layer 1: proj (all t), gathers, fused out+LN ----
    k_projm3<<<(C2n / 16 + 3) / 4, 256, 0, stream>>>(x, Wp, bp, xp3);
    for (int t = 0; t < 3; t++)
        k_gath1<<<(C1n + 3) / 4, 256, 0, stream>>>(rp1 + (size_t)t * C1n,
                                                   el1 + (size_t)t * NEn,
                                                   xp3 + (size_t)t * C2n * 64,
                                                   agg3 + (size_t)t * C1n * 64);
    k_out1f<<<(C1n / 16 + 3) / 4, 256, 0, stream>>>(agg3, x, Wl, Wr, bl, g0, b0, h1);

    // ---- CSR layer 2 (first E0 edges, nV=C0) ----
    hipMemsetAsync(rp2, 0, 2 * 3 * (size_t)C0n * 4, stream);   // rp2 + fill2
    hipMemsetAsync(cnt2, 0, 3 * (size_t)NB2 * 4, stream);
    k_hist<<<dim3((E0n + 255) / 256, 3), 256, 0, stream>>>(
        ei[0] + NEn, ei[1] + NEn, ei[2] + NEn, rp2, E0n, C0n);
    k_scan_a<<<dim3(nb2, 3), 256, 0, stream>>>(rp2, C0n, bsum, nb2);
    k_scan_b<<<dim3(1, 3), 256, 0, stream>>>(bsum, nb2);
    k_scan_c<<<dim3(nb2, 3), 256, 0, stream>>>(rp2, C0n, bsum, nb2);
    k_bfill1<<<dim3((E0n + 255) / 256, 3), 256, 0, stream>>>(
        ei[0], ei[1], ei[2], ei[0] + NEn, ei[1] + NEn, ei[2] + NEn,
        rp2, cnt2, ebuf2, E0n, C0n, NB2);
    k_bfill2<<<dim3(NB2, 3), 256, 0, stream>>>(rp2, fill2, ebuf2, el2, E0n, C0n, NB2);

    // ---- layer 2: gathers, fused out+LN -> d_out ----
    for (int t = 0; t < 3; t++)
        k_gath2<<<(C0n + 3) / 4, 256, 0, stream>>>(rp2 + (size_t)t * C0n,
                                                   el2 + (size_t)t * E0n, h1,
                                                   agg2 + (size_t)t * C0n * 128);
    k_out2f<<<(C0n / 16 + 3) / 4, 256, 0, stream>>>(agg2, h1, Wl2, Wr2, bl2, g1, b1,
                                                    (float*)d_out);
}

// Round 12
// 949.495 us; speedup vs baseline: 2.1400x; 2.1400x over previous
//
#include <hip/hip_runtime.h>

#define C0n 50000
#define C1n 150000
#define C2n 300000
#define E0n 300000
#define E1n 600000
#define NEn (E0n + E1n)
#define PAD64 76     // 64-col weight tile stride (u16): 152B = 38 words, 38%32=6 -> ~2-way
#define PAD128 140   // 128-col weight tile stride (u16): 280B = 70 words, 70%32=6 -> ~2-way

typedef float  v4f    __attribute__((ext_vector_type(4)));
typedef float  v2f    __attribute__((ext_vector_type(2)));
typedef float  f32x4  __attribute__((ext_vector_type(4)));
typedef short  bf16x8 __attribute__((ext_vector_type(8)));
typedef unsigned short u16;

__device__ __forceinline__ u16 f2bf(float f){
    unsigned u = __builtin_bit_cast(unsigned, f);
    u += 0x7FFFu + ((u >> 16) & 1u);          // RNE
    return (u16)(u >> 16);
}
__device__ __forceinline__ float bf2f(u16 h){
    unsigned u = ((unsigned)h) << 16;
    return __builtin_bit_cast(float, u);
}
__device__ __forceinline__ f32x4 mfma16(bf16x8 a, bf16x8 b, f32x4 c){
    return __builtin_amdgcn_mfma_f32_16x16x32_bf16(a, b, c, 0, 0, 0);
}
__device__ __forceinline__ float red16(float v){
    v += __shfl_xor(v, 1); v += __shfl_xor(v, 2);
    v += __shfl_xor(v, 4); v += __shfl_xor(v, 8);
    return v;
}
// 8 consecutive f32 -> bf16x8 fragment (16B-aligned source)
__device__ __forceinline__ bf16x8 frag8(const float* __restrict__ p){
    v4f a = *(const v4f*)p, b = *(const v4f*)(p + 4);
    bf16x8 r;
    r[0] = (short)f2bf(a[0]); r[1] = (short)f2bf(a[1]);
    r[2] = (short)f2bf(a[2]); r[3] = (short)f2bf(a[3]);
    r[4] = (short)f2bf(b[0]); r[5] = (short)f2bf(b[1]);
    r[6] = (short)f2bf(b[2]); r[7] = (short)f2bf(b[3]);
    return r;
}

// ------- xp_t = relu(x @ Wp[t] + bp[t]) for ALL t (r8-validated, guarded tiles) -------
__global__ __launch_bounds__(256) void k_projm3(const float* __restrict__ x,
    const float* __restrict__ Wp, const float* __restrict__ bp,
    u16* __restrict__ xp3)
{
    __shared__ u16 Wt[3][64 * PAD64];   // [t][c][k]
    __shared__ float bps[3 * 64];
    const int tid = threadIdx.x;
    for (int i = tid; i < 192; i += 256) bps[i] = bp[i];
    for (int t = 0; t < 3; t++)
        for (int idx = tid; idx < 64 * 64; idx += 256) {
            int k = idx >> 6, c = idx & 63;      // idx = k*64 + c
            Wt[t][c * PAD64 + k] = f2bf(Wp[t * 4096 + idx]);
        }
    __syncthreads();

    const int lane = tid & 63, wid = tid >> 6;
    const int lr = lane & 15, lg = lane >> 4;
    const int ntiles = C2n / 16;                  // 18750
    int rt = blockIdx.x * 4 + wid;
    const bool valid = (rt < ntiles);
    if (rt > ntiles - 1) rt = ntiles - 1;         // clamp for loads only
    const int r0 = rt * 16;

    // x fragments: t-invariant, load once
    bf16x8 xa[2];
    xa[0] = frag8(&x[(size_t)(r0 + lr) * 64 + 0  + 8 * lg]);
    xa[1] = frag8(&x[(size_t)(r0 + lr) * 64 + 32 + 8 * lg]);

    for (int t = 0; t < 3; t++) {
        f32x4 acc[4];
#pragma unroll
        for (int n = 0; n < 4; n++) acc[n] = 0;
#pragma unroll
        for (int ks = 0; ks < 2; ks++) {
#pragma unroll
            for (int n = 0; n < 4; n++) {
                bf16x8 b = *(const bf16x8*)&Wt[t][(16 * n + lr) * PAD64 + ks * 32 + 8 * lg];
                acc[n] = mfma16(xa[ks], b, acc[n]);
            }
        }
        if (valid) {
            u16* xp = xp3 + (size_t)t * C2n * 64;
#pragma unroll
            for (int n = 0; n < 4; n++) {
                const float bb = bps[t * 64 + 16 * n + lr];
#pragma unroll
                for (int j = 0; j < 4; j++)
                    xp[(size_t)(r0 + 4 * lg + j) * 64 + 16 * n + lr] =
                        f2bf(fmaxf(acc[n][j] + bb, 0.f));
            }
        }
    }
}

// ---------------- CSR build: histogram ----------------
__global__ __launch_bounds__(256) void k_hist(const int* __restrict__ d0,
    const int* __restrict__ d1, const int* __restrict__ d2,
    int* __restrict__ deg, int nE, int nV)
{
    const int e = blockIdx.x * 256 + threadIdx.x;
    if (e >= nE) return;
    const int y = blockIdx.y;
    const int* d = (y == 0) ? d0 : (y == 1) ? d1 : d2;
    atomicAdd(&deg[(size_t)y * nV + d[e]], 1);
}

// ---------------- CSR build: exclusive scan ----------------
__global__ __launch_bounds__(256) void k_scan_a(int* __restrict__ a, int n,
    int* __restrict__ bsum, int nblk)
{
    __shared__ int sd[256];
    const int t = threadIdx.x, y = blockIdx.y;
    int* arr = a + (size_t)y * n;
    const int base = blockIdx.x * 2048 + t * 8;
    int v[8];
#pragma unroll
    for (int j = 0; j < 8; j++) v[j] = (base + j < n) ? arr[base + j] : 0;
    int tot = 0;
#pragma unroll
    for (int j = 0; j < 8; j++) { int tmp = v[j]; v[j] = tot; tot += tmp; }
    sd[t] = tot; __syncthreads();
    for (int off = 1; off < 256; off <<= 1) {
        int xv = (t >= off) ? sd[t - off] : 0;
        __syncthreads();
        sd[t] += xv;
        __syncthreads();
    }
    const int excl = sd[t] - tot;
#pragma unroll
    for (int j = 0; j < 8; j++)
        if (base + j < n) arr[base + j] = excl + v[j];
    if (t == 255) bsum[y * nblk + blockIdx.x] = sd[255];
}

__global__ __launch_bounds__(256) void k_scan_b(int* __restrict__ bsum, int nblk)
{
    __shared__ int sd[256];
    const int t = threadIdx.x, y = blockIdx.y;
    int val = (t < nblk) ? bsum[y * nblk + t] : 0;
    sd[t] = val; __syncthreads();
    for (int off = 1; off < 256; off <<= 1) {
        int xv = (t >= off) ? sd[t - off] : 0;
        __syncthreads();
        sd[t] += xv;
        __syncthreads();
    }
    if (t < nblk) bsum[y * nblk + t] = sd[t] - val;
}

__global__ __launch_bounds__(256) void k_scan_c(int* __restrict__ a, int n,
    const int* __restrict__ bsum, int nblk)
{
    const int t = threadIdx.x, y = blockIdx.y;
    int* arr = a + (size_t)y * n;
    const int base = blockIdx.x * 2048 + t * 8;
    const int add = bsum[y * nblk + blockIdx.x];
#pragma unroll
    for (int j = 0; j < 8; j++)
        if (base + j < n) arr[base + j] += add;
}

// ---------------- CSR build: fill (r8-validated) ----------------
__global__ __launch_bounds__(256) void k_fill(const int* __restrict__ s0,
    const int* __restrict__ s1, const int* __restrict__ s2,
    const int* __restrict__ d0, const int* __restrict__ d1, const int* __restrict__ d2,
    const int* __restrict__ rp, int* __restrict__ fill, int* __restrict__ el,
    int nE, int nV)
{
    const int e = blockIdx.x * 256 + threadIdx.x;
    if (e >= nE) return;
    const int y = blockIdx.y;
    const int* s = (y == 0) ? s0 : (y == 1) ? s1 : s2;
    const int* d = (y == 0) ? d0 : (y == 1) ? d1 : d2;
    const int dd = d[e];
    const int pos = rp[(size_t)y * nV + dd] + atomicAdd(&fill[(size_t)y * nV + dd], 1);
    el[(size_t)y * nE + pos] = s[e];
}

// ---------------- gather layer1: agg_t[r] = mean of xp_t[src] (bf16 -> bf16) ----------------
__global__ __launch_bounds__(256) void k_gath1(const int* __restrict__ rp,
    const int* __restrict__ el, const u16* __restrict__ xp,
    u16* __restrict__ aggt)
{
    const int gid = blockIdx.x * 4 + (threadIdx.x >> 6);
    if (gid >= C1n) return;
    const int lane = threadIdx.x & 63;
    const int b = rp[gid];
    const int e = (gid == C1n - 1) ? NEn : rp[gid + 1];
    float s = 0.f;
    for (int i = b; i < e; i++) {
        const int sr = el[i];
        s += bf2f(xp[(size_t)sr * 64 + lane]);
    }
    const float inv = 1.f / (float)max(e - b, 1);
    aggt[(size_t)gid * 64 + lane] = f2bf(s * inv);
}

// ------- fused layer1 (r8-validated): per-t staging, 256 thr, valid-guard;
//         h1 = LN(relu(sum/3)) written ONCE as bf16 -------
__global__ __launch_bounds__(256) void k_out1f(const u16* __restrict__ agg3,
    const float* __restrict__ x,
    const float* __restrict__ Wl, const float* __restrict__ Wr,
    const float* __restrict__ bl,
    const float* __restrict__ g0, const float* __restrict__ b0,
    u16* __restrict__ h1)
{
    __shared__ u16 Wt[128 * PAD128];   // [c][k]
    __shared__ float bls[3 * 128], gs[128], bs[128];
    const int tid = threadIdx.x;
    if (tid < 128) { gs[tid] = g0[tid]; bs[tid] = b0[tid]; }
    for (int i = tid; i < 384; i += 256) bls[i] = bl[i];

    const int lane = tid & 63, wid = tid >> 6;
    const int lr = lane & 15, lg = lane >> 4;
    const int ntiles = C1n / 16;                  // 9375
    int rt = blockIdx.x * 4 + wid;
    const bool valid = (rt < ntiles);
    if (rt > ntiles - 1) rt = ntiles - 1;         // clamp for loads only
    const int r0 = rt * 16;

    // x fragments: t-invariant, load once
    bf16x8 xa[2];
    xa[0] = frag8(&x[(size_t)(r0 + lr) * 64 + 0  + 8 * lg]);
    xa[1] = frag8(&x[(size_t)(r0 + lr) * 64 + 32 + 8 * lg]);

    f32x4 hacc[8];
#pragma unroll
    for (int n = 0; n < 8; n++) hacc[n] = 0;

    for (int t = 0; t < 3; t++) {
        __syncthreads();                          // Wt reuse protection
        const float* WlT = Wl + (size_t)t * 64 * 128;
        const float* WrT = Wr + (size_t)t * 64 * 128;
        for (int idx = tid; idx < 128 * 128; idx += 256) {
            int k = idx >> 7, c = idx & 127;
            float w = (k < 64) ? WlT[k * 128 + c] : WrT[(k - 64) * 128 + c];
            Wt[c * PAD128 + k] = f2bf(w);
        }
        __syncthreads();

        const u16* aggT = agg3 + (size_t)t * C1n * 64;
        f32x4 ta[8];
#pragma unroll
        for (int n = 0; n < 8; n++) ta[n] = 0;
#pragma unroll
        for (int ks = 0; ks < 4; ks++) {
            bf16x8 a;
            if (ks < 2)
                a = *(const bf16x8*)&aggT[(size_t)(r0 + lr) * 64 + ks * 32 + 8 * lg];
            else
                a = xa[ks - 2];
#pragma unroll
            for (int n = 0; n < 8; n++) {
                bf16x8 b = *(const bf16x8*)&Wt[(16 * n + lr) * PAD128 + ks * 32 + 8 * lg];
                ta[n] = mfma16(a, b, ta[n]);
            }
        }
        // + bias, row L2 norm (row = 4*lg + j; cols spread over 16 lanes x 8 n-tiles)
        float ss[4] = {0.f, 0.f, 0.f, 0.f};
#pragma unroll
        for (int n = 0; n < 8; n++) {
            const float bb = bls[t * 128 + 16 * n + lr];
#pragma unroll
            for (int j = 0; j < 4; j++) {
                ta[n][j] += bb;
                ss[j] += ta[n][j] * ta[n][j];
            }
        }
#pragma unroll
        for (int j = 0; j < 4; j++)
            ss[j] = 1.f / fmaxf(sqrtf(red16(ss[j])), 1e-12f);
#pragma unroll
        for (int n = 0; n < 8; n++)
#pragma unroll
            for (int j = 0; j < 4; j++) hacc[n][j] += ta[n][j] * ss[j];
    }

    // relu + /3 + LayerNorm over 128 cols
    float mu[4] = {0.f, 0.f, 0.f, 0.f};
#pragma unroll
    for (int n = 0; n < 8; n++)
#pragma unroll
        for (int j = 0; j < 4; j++) {
            float v = fmaxf(hacc[n][j], 0.f) * (1.f / 3.f);
            hacc[n][j] = v; mu[j] += v;
        }
#pragma unroll
    for (int j = 0; j < 4; j++) mu[j] = red16(mu[j]) * (1.f / 128.f);
    float var[4] = {0.f, 0.f, 0.f, 0.f};
#pragma unroll
    for (int n = 0; n < 8; n++)
#pragma unroll
        for (int j = 0; j < 4; j++) {
            float d = hacc[n][j] - mu[j]; var[j] += d * d;
        }
#pragma unroll
    for (int j = 0; j < 4; j++) var[j] = rsqrtf(red16(var[j]) * (1.f / 128.f) + 1e-5f);

    if (valid) {
#pragma unroll
        for (int n = 0; n < 8; n++) {
            const float g = gs[16 * n + lr], bb = bs[16 * n + lr];
#pragma unroll
            for (int j = 0; j < 4; j++) {
                float o = (hacc[n][j] - mu[j]) * var[j] * g + bb;
                h1[(size_t)(r0 + 4 * lg + j) * 128 + 16 * n + lr] = f2bf(o);
            }
        }
    }
}

// ---------------- gather layer2: agg2_t[r] = mean of h1[src] (bf16 -> bf16) ----------------
__global__ __launch_bounds__(256) void k_gath2(const int* __restrict__ rp,
    const int* __restrict__ el, const u16* __restrict__ h1,
    u16* __restrict__ agg2t)
{
    const int gid = blockIdx.x * 4 + (threadIdx.x >> 6);
    if (gid >= C0n) return;
    const int lane = threadIdx.x & 63;
    const int b = rp[gid];
    const int e = (gid == C0n - 1) ? E0n : rp[gid + 1];
    float s0 = 0.f, s1 = 0.f;
    for (int i = b; i < e; i++) {
        const int sr = el[i];
        unsigned u = *(const unsigned*)&h1[(size_t)sr * 128 + lane * 2];
        s0 += bf2f((u16)(u & 0xffffu));
        s1 += bf2f((u16)(u >> 16));
    }
    const float inv = 1.f / (float)max(e - b, 1);
    unsigned o = (unsigned)f2bf(s0 * inv) | ((unsigned)f2bf(s1 * inv) << 16);
    *(unsigned*)&agg2t[(size_t)gid * 128 + lane * 2] = o;
}

// ------- fused layer2 (r8-validated): per-t/hh staging, 256 thr, valid-guard -------
__global__ __launch_bounds__(256) void k_out2f(const u16* __restrict__ agg2,
    const u16* __restrict__ h1,
    const float* __restrict__ Wl2, const float* __restrict__ Wr2,
    const float* __restrict__ bl2,
    const float* __restrict__ g1, const float* __restrict__ b1,
    float* __restrict__ out)
{
    __shared__ u16 Wt[128 * PAD128];
    __shared__ float bsm[128], gs[128], bs[128];
    const int tid = threadIdx.x;
    if (tid < 128) {
        gs[tid] = g1[tid]; bs[tid] = b1[tid];
        bsm[tid] = bl2[tid] + bl2[128 + tid] + bl2[256 + tid];
    }
    const int lane = tid & 63, wid = tid >> 6;
    const int lr = lane & 15, lg = lane >> 4;
    const int ntiles = C0n / 16;                  // 3125
    int rt = blockIdx.x * 4 + wid;
    const bool valid = (rt < ntiles);
    if (rt > ntiles - 1) rt = ntiles - 1;         // clamp for loads only
    const int r0 = rt * 16;

    // h1 fragments: t-invariant, load once (bf16 direct)
    bf16x8 ha[4];
#pragma unroll
    for (int ks = 0; ks < 4; ks++)
        ha[ks] = *(const bf16x8*)&h1[(size_t)(r0 + lr) * 128 + ks * 32 + 8 * lg];

    f32x4 acc[8];
#pragma unroll
    for (int n = 0; n < 8; n++) acc[n] = 0;

    for (int t = 0; t < 3; t++) {
        for (int hh = 0; hh < 2; hh++) {
            __syncthreads();                      // Wt reuse protection
            const float* W = hh ? Wr2 + (size_t)t * 128 * 128
                                : Wl2 + (size_t)t * 128 * 128;
            for (int idx = tid; idx < 128 * 128; idx += 256) {
                int k = idx >> 7, c = idx & 127;
                Wt[c * PAD128 + k] = f2bf(W[idx]);   // idx = k*128 + c
            }
            __syncthreads();
#pragma unroll
            for (int ks = 0; ks < 4; ks++) {
                bf16x8 a;
                if (hh == 0)
                    a = *(const bf16x8*)&agg2[(size_t)t * C0n * 128 +
                                              (size_t)(r0 + lr) * 128 + ks * 32 + 8 * lg];
                else
                    a = ha[ks];
#pragma unroll
                for (int n = 0; n < 8; n++) {
                    bf16x8 b = *(const bf16x8*)&Wt[(16 * n + lr) * PAD128 + ks * 32 + 8 * lg];
                    acc[n] = mfma16(a, b, acc[n]);
                }
            }
        }
    }

    // (acc + Σbias)/3, relu, LN
    float mu[4] = {0.f, 0.f, 0.f, 0.f};
#pragma unroll
    for (int n = 0; n < 8; n++) {
        const float bb = bsm[16 * n + lr];
#pragma unroll
        for (int j = 0; j < 4; j++) {
            float v = fmaxf((acc[n][j] + bb) * (1.f / 3.f), 0.f);
            acc[n][j] = v; mu[j] += v;
        }
    }
#pragma unroll
    for (int j = 0; j < 4; j++) mu[j] = red16(mu[j]) * (1.f / 128.f);
    float var[4] = {0.f, 0.f, 0.f, 0.f};
#pragma unroll
    for (int n = 0; n < 8; n++)
#pragma unroll
        for (int j = 0; j < 4; j++) {
            float d = acc[n][j] - mu[j]; var[j] += d * d;
        }
#pragma unroll
    for (int j = 0; j < 4; j++) var[j] = rsqrtf(red16(var[j]) * (1.f / 128.f) + 1e-5f);

    if (valid) {
#pragma unroll
        for (int n = 0; n < 8; n++) {
            const float g = gs[16 * n + lr], bb = bs[16 * n + lr];
#pragma unroll
            for (int j = 0; j < 4; j++) {
                float o = (acc[n][j] - mu[j]) * var[j] * g + bb;
                out[(size_t)(r0 + 4 * lg + j) * 128 + 16 * n + lr] = o;
            }
        }
    }
}

extern "C" void kernel_launch(void* const* d_in, const int* in_sizes, int n_in,
                              void* d_out, int out_size, void* d_ws, size_t ws_size,
                              hipStream_t stream)
{
    const float* x   = (const float*)d_in[0];
    const int*   ei[3] = { (const int*)d_in[1], (const int*)d_in[2], (const int*)d_in[3] };
    const float* Wp  = (const float*)d_in[6];
    const float* bp  = (const float*)d_in[7];
    const float* Wl  = (const float*)d_in[8];
    const float* bl  = (const float*)d_in[9];
    const float* Wr  = (const float*)d_in[10];
    const float* Wl2 = (const float*)d_in[11];
    const float* bl2 = (const float*)d_in[12];
    const float* Wr2 = (const float*)d_in[13];
    const float* g0  = (const float*)d_in[14];
    const float* b0  = (const float*)d_in[15];
    const float* g1  = (const float*)d_in[16];
    const float* b1  = (const float*)d_in[17];

    // ---- workspace layout (bytes) ----
    char* W = (char*)d_ws;
    u16*   agg3 = (u16*)(W + 0);             // 3*C1*64 bf16 = 57,600,000
    u16*   xp3  = (u16*)(W + 57600000);      // 3*C2*64 bf16 = 115,200,000 -> 172,800,000
    u16*   h1   = (u16*)(W + 57600000);      // C1*128 bf16 = 38,400,000 (overlays xp3 t=0)
    int*   rp1  = (int*)(W + 172800000);     // 3*C1*4 = 1,800,000
    int*   fill1= (int*)(W + 174600000);     // 1,800,000
    int*   bsum = (int*)(W + 176400000);     // 4 KiB
    int*   el1  = (int*)(W + 176404096);     // 3*NE*4 = 10,800,000 -> ends 187,204,096
    // layer-2 overlays: agg3 dead after out1f
    u16*   agg2 = (u16*)(W + 0);             // 3*C0*128 bf16 = 38,400,000
    int*   rp2  = (int*)(W + 38400000);      // 600,000
    int*   fill2= (int*)(W + 39000000);      // 600,000
    int*   el2  = (int*)(W + 39600000);      // 3*E0*4 = 3,600,000 -> ends 43,200,000

    const int nb1 = (C1n + 2047) / 2048;  // 74
    const int nb2 = (C0n + 2047) / 2048;  // 25

    // ---- CSR layer 1 (dst over full edge list, nV=C1) ----
    hipMemsetAsync(rp1, 0, 2 * 3 * (size_t)C1n * 4, stream);   // rp1 + fill1
    k_hist<<<dim3((NEn + 255) / 256, 3), 256, 0, stream>>>(
        ei[0] + NEn, ei[1] + NEn, ei[2] + NEn, rp1, NEn, C1n);
    k_scan_a<<<dim3(nb1, 3), 256, 0, stream>>>(rp1, C1n, bsum, nb1);
    k_scan_b<<<dim3(1, 3), 256, 0, stream>>>(bsum, nb1);
    k_scan_c<<<dim3(nb1, 3), 256, 0, stream>>>(rp1, C1n, bsum, nb1);
    k_fill<<<dim3((NEn + 255) / 256, 3), 256, 0, stream>>>(
        ei[0], ei[1], ei[2], ei[0] + NEn, ei[1] + NEn, ei[2] + NEn,
        rp1, fill1, el1, NEn, C1n);

    // ---- layer 1: one proj for all t, gathers, fused out+LN ----
    k_projm3<<<(C2n / 16 + 3) / 4, 256, 0, stream>>>(x, Wp, bp, xp3);
    for (int t = 0; t < 3; t++)
        k_gath1<<<(C1n + 3) / 4, 256, 0, stream>>>(rp1 + (size_t)t * C1n,
                                                   el1 + (size_t)t * NEn,
                                                   xp3 + (size_t)t * C2n * 64,
                                                   agg3 + (size_t)t * C1n * 64);
    k_out1f<<<(C1n / 16 + 3) / 4, 256, 0, stream>>>(agg3, x, Wl, Wr, bl, g0, b0, h1);

    // ---- CSR layer 2 (first E0 edges, nV=C0) ----
    hipMemsetAsync(rp2, 0, 2 * 3 * (size_t)C0n * 4, stream);   // rp2 + fill2
    k_hist<<<dim3((E0n + 255) / 256, 3), 256, 0, stream>>>(
        ei[0] + NEn, ei[1] + NEn, ei[2] + NEn, rp2, E0n, C0n);
    k_scan_a<<<dim3(nb2, 3), 256, 0, stream>>>(rp2, C0n, bsum, nb2);
    k_scan_b<<<dim3(1, 3), 256, 0, stream>>>(bsum, nb2);
    k_scan_c<<<dim3(nb2, 3), 256, 0, stream>>>(rp2, C0n, bsum, nb2);
    k_fill<<<dim3((E0n + 255) / 256, 3), 256, 0, stream>>>(
        ei[0], ei[1], ei[2], ei[0] + NEn, ei[1] + NEn, ei[2] + NEn,
        rp2, fill2, el2, E0n, C0n);

    // ---- layer 2: gathers, fused out+LN -> d_out ----
    for (int t = 0; t < 3; t++)
        k_gath2<<<(C0n + 3) / 4, 256, 0, stream>>>(rp2 + (size_t)t * C0n,
                                                   el2 + (size_t)t * E0n, h1,
                                                   agg2 + (size_t)t * C0n * 128);
    k_out2f<<<(C0n / 16 + 3) / 4, 256, 0, stream>>>(agg2, h1, Wl2, Wr2, bl2, g1, b1,
                                                    (float*)d_out);
}

// Round 13
// 872.533 us; speedup vs baseline: 2.3287x; 1.0882x over previous
//
#include <hip/hip_runtime.h>

#define C0n 50000
#define C1n 150000
#define C2n 300000
#define E0n 300000
#define E1n 600000
#define NEn (E0n + E1n)
#define PAD64 76     // 64-col weight tile stride (u16): 152B = 38 words, 38%32=6 -> ~2-way
#define PAD128 140   // 128-col weight tile stride (u16): 280B = 70 words, 70%32=6 -> ~2-way

typedef float  v4f    __attribute__((ext_vector_type(4)));
typedef float  v2f    __attribute__((ext_vector_type(2)));
typedef float  f32x4  __attribute__((ext_vector_type(4)));
typedef short  bf16x8 __attribute__((ext_vector_type(8)));
typedef unsigned short u16;

__device__ __forceinline__ u16 f2bf(float f){
    unsigned u = __builtin_bit_cast(unsigned, f);
    u += 0x7FFFu + ((u >> 16) & 1u);          // RNE
    return (u16)(u >> 16);
}
__device__ __forceinline__ float bf2f(u16 h){
    unsigned u = ((unsigned)h) << 16;
    return __builtin_bit_cast(float, u);
}
__device__ __forceinline__ f32x4 mfma16(bf16x8 a, bf16x8 b, f32x4 c){
    return __builtin_amdgcn_mfma_f32_16x16x32_bf16(a, b, c, 0, 0, 0);
}
__device__ __forceinline__ float red16(float v){
    v += __shfl_xor(v, 1); v += __shfl_xor(v, 2);
    v += __shfl_xor(v, 4); v += __shfl_xor(v, 8);
    return v;
}
// 8 consecutive f32 -> bf16x8 fragment (16B-aligned source)
__device__ __forceinline__ bf16x8 frag8(const float* __restrict__ p){
    v4f a = *(const v4f*)p, b = *(const v4f*)(p + 4);
    bf16x8 r;
    r[0] = (short)f2bf(a[0]); r[1] = (short)f2bf(a[1]);
    r[2] = (short)f2bf(a[2]); r[3] = (short)f2bf(a[3]);
    r[4] = (short)f2bf(b[0]); r[5] = (short)f2bf(b[1]);
    r[6] = (short)f2bf(b[2]); r[7] = (short)f2bf(b[3]);
    return r;
}

// ------- one-shot: pre-transpose + pre-pad + pre-bf16 all weights into caches -------
// Wp_c : [3][64][PAD64]    (Wp^T per t)
// W1_c : [3][128][PAD128]  ([Wl;Wr]^T per t, k<64 = Wl, 64<=k<128 = Wr)
// W2_c : [6][128][PAD128]  (t<3: Wl2_t^T ; t>=3: Wr2_{t-3}^T)
__global__ __launch_bounds__(256) void k_wconv(const float* __restrict__ Wp,
    const float* __restrict__ Wl, const float* __restrict__ Wr,
    const float* __restrict__ Wl2, const float* __restrict__ Wr2,
    u16* __restrict__ Wp_c, u16* __restrict__ W1_c, u16* __restrict__ W2_c)
{
    const int i0 = blockIdx.x * 256 + threadIdx.x;
    const int stride = gridDim.x * 256;
    for (int idx = i0; idx < 3 * 64 * PAD64; idx += stride) {
        int t = idx / (64 * PAD64), r = idx % (64 * PAD64);
        int c = r / PAD64, k = r % PAD64;
        Wp_c[idx] = (k < 64) ? f2bf(Wp[t * 4096 + k * 64 + c]) : (u16)0;
    }
    for (int idx = i0; idx < 3 * 128 * PAD128; idx += stride) {
        int t = idx / (128 * PAD128), r = idx % (128 * PAD128);
        int c = r / PAD128, k = r % PAD128;
        u16 v = 0;
        if (k < 64)       v = f2bf(Wl[t * 8192 + k * 128 + c]);
        else if (k < 128) v = f2bf(Wr[t * 8192 + (k - 64) * 128 + c]);
        W1_c[idx] = v;
    }
    for (int idx = i0; idx < 6 * 128 * PAD128; idx += stride) {
        int m = idx / (128 * PAD128), r = idx % (128 * PAD128);
        int t = m % 3;
        const float* W = (m >= 3) ? Wr2 : Wl2;
        int c = r / PAD128, k = r % PAD128;
        W2_c[idx] = (k < 128) ? f2bf(W[t * 16384 + k * 128 + c]) : (u16)0;
    }
}

// ------- xp_t = relu(x @ Wp[t] + bp[t]) for ALL t (staging = vector memcpy) -------
__global__ __launch_bounds__(256) void k_projm3(const float* __restrict__ x,
    const u16* __restrict__ Wp_c, const float* __restrict__ bp,
    u16* __restrict__ xp3)
{
    __shared__ __align__(16) u16 Wt[3 * 64 * PAD64];   // 29,184 B
    __shared__ float bps[3 * 64];
    const int tid = threadIdx.x;
    for (int i = tid; i < 192; i += 256) bps[i] = bp[i];
    for (int i = tid; i < 3 * 64 * PAD64 / 8; i += 256)      // 1824 16B copies
        ((bf16x8*)Wt)[i] = ((const bf16x8*)Wp_c)[i];
    __syncthreads();

    const int lane = tid & 63, wid = tid >> 6;
    const int lr = lane & 15, lg = lane >> 4;
    const int ntiles = C2n / 16;                  // 18750
    int rt = blockIdx.x * 4 + wid;
    const bool valid = (rt < ntiles);
    if (rt > ntiles - 1) rt = ntiles - 1;         // clamp for loads only
    const int r0 = rt * 16;

    // x fragments: t-invariant, load once
    bf16x8 xa[2];
    xa[0] = frag8(&x[(size_t)(r0 + lr) * 64 + 0  + 8 * lg]);
    xa[1] = frag8(&x[(size_t)(r0 + lr) * 64 + 32 + 8 * lg]);

    for (int t = 0; t < 3; t++) {
        f32x4 acc[4];
#pragma unroll
        for (int n = 0; n < 4; n++) acc[n] = 0;
#pragma unroll
        for (int ks = 0; ks < 2; ks++) {
#pragma unroll
            for (int n = 0; n < 4; n++) {
                bf16x8 b = *(const bf16x8*)&Wt[t * 64 * PAD64 + (16 * n + lr) * PAD64 + ks * 32 + 8 * lg];
                acc[n] = mfma16(xa[ks], b, acc[n]);
            }
        }
        if (valid) {
            u16* xp = xp3 + (size_t)t * C2n * 64;
#pragma unroll
            for (int n = 0; n < 4; n++) {
                const float bb = bps[t * 64 + 16 * n + lr];
#pragma unroll
                for (int j = 0; j < 4; j++)
                    xp[(size_t)(r0 + 4 * lg + j) * 64 + 16 * n + lr] =
                        f2bf(fmaxf(acc[n][j] + bb, 0.f));
            }
        }
    }
}

// ---------------- CSR build: histogram ----------------
__global__ __launch_bounds__(256) void k_hist(const int* __restrict__ d0,
    const int* __restrict__ d1, const int* __restrict__ d2,
    int* __restrict__ deg, int nE, int nV)
{
    const int e = blockIdx.x * 256 + threadIdx.x;
    if (e >= nE) return;
    const int y = blockIdx.y;
    const int* d = (y == 0) ? d0 : (y == 1) ? d1 : d2;
    atomicAdd(&deg[(size_t)y * nV + d[e]], 1);
}

// ---------------- CSR build: exclusive scan ----------------
__global__ __launch_bounds__(256) void k_scan_a(int* __restrict__ a, int n,
    int* __restrict__ bsum, int nblk)
{
    __shared__ int sd[256];
    const int t = threadIdx.x, y = blockIdx.y;
    int* arr = a + (size_t)y * n;
    const int base = blockIdx.x * 2048 + t * 8;
    int v[8];
#pragma unroll
    for (int j = 0; j < 8; j++) v[j] = (base + j < n) ? arr[base + j] : 0;
    int tot = 0;
#pragma unroll
    for (int j = 0; j < 8; j++) { int tmp = v[j]; v[j] = tot; tot += tmp; }
    sd[t] = tot; __syncthreads();
    for (int off = 1; off < 256; off <<= 1) {
        int xv = (t >= off) ? sd[t - off] : 0;
        __syncthreads();
        sd[t] += xv;
        __syncthreads();
    }
    const int excl = sd[t] - tot;
#pragma unroll
    for (int j = 0; j < 8; j++)
        if (base + j < n) arr[base + j] = excl + v[j];
    if (t == 255) bsum[y * nblk + blockIdx.x] = sd[255];
}

__global__ __launch_bounds__(256) void k_scan_b(int* __restrict__ bsum, int nblk)
{
    __shared__ int sd[256];
    const int t = threadIdx.x, y = blockIdx.y;
    int val = (t < nblk) ? bsum[y * nblk + t] : 0;
    sd[t] = val; __syncthreads();
    for (int off = 1; off < 256; off <<= 1) {
        int xv = (t >= off) ? sd[t - off] : 0;
        __syncthreads();
        sd[t] += xv;
        __syncthreads();
    }
    if (t < nblk) bsum[y * nblk + t] = sd[t] - val;
}

__global__ __launch_bounds__(256) void k_scan_c(int* __restrict__ a, int n,
    const int* __restrict__ bsum, int nblk)
{
    const int t = threadIdx.x, y = blockIdx.y;
    int* arr = a + (size_t)y * n;
    const int base = blockIdx.x * 2048 + t * 8;
    const int add = bsum[y * nblk + blockIdx.x];
#pragma unroll
    for (int j = 0; j < 8; j++)
        if (base + j < n) arr[base + j] += add;
}

// ---------------- CSR build: fill (r8-validated) ----------------
__global__ __launch_bounds__(256) void k_fill(const int* __restrict__ s0,
    const int* __restrict__ s1, const int* __restrict__ s2,
    const int* __restrict__ d0, const int* __restrict__ d1, const int* __restrict__ d2,
    const int* __restrict__ rp, int* __restrict__ fill, int* __restrict__ el,
    int nE, int nV)
{
    const int e = blockIdx.x * 256 + threadIdx.x;
    if (e >= nE) return;
    const int y = blockIdx.y;
    const int* s = (y == 0) ? s0 : (y == 1) ? s1 : s2;
    const int* d = (y == 0) ? d0 : (y == 1) ? d1 : d2;
    const int dd = d[e];
    const int pos = rp[(size_t)y * nV + dd] + atomicAdd(&fill[(size_t)y * nV + dd], 1);
    el[(size_t)y * nE + pos] = s[e];
}

// ---------------- gather layer1: agg_t[r] = mean of xp_t[src] (bf16 -> bf16) ----------------
__global__ __launch_bounds__(256) void k_gath1(const int* __restrict__ rp,
    const int* __restrict__ el, const u16* __restrict__ xp,
    u16* __restrict__ aggt)
{
    const int gid = blockIdx.x * 4 + (threadIdx.x >> 6);
    if (gid >= C1n) return;
    const int lane = threadIdx.x & 63;
    const int b = rp[gid];
    const int e = (gid == C1n - 1) ? NEn : rp[gid + 1];
    float s = 0.f;
    for (int i = b; i < e; i++) {
        const int sr = el[i];
        s += bf2f(xp[(size_t)sr * 64 + lane]);
    }
    const float inv = 1.f / (float)max(e - b, 1);
    aggt[(size_t)gid * 64 + lane] = f2bf(s * inv);
}

// ------- fused layer1: per t { o=[agg_t|x]@[Wl;Wr]+bl; o/=||o|| ; accumulate } ;
//         h1 = LN(relu(sum/3)) bf16. Staging = vector memcpy from W1_c. -------
__global__ __launch_bounds__(256) void k_out1f(const u16* __restrict__ agg3,
    const float* __restrict__ x, const u16* __restrict__ W1_c,
    const float* __restrict__ bl,
    const float* __restrict__ g0, const float* __restrict__ b0,
    u16* __restrict__ h1)
{
    __shared__ __align__(16) u16 Wt[128 * PAD128];   // 35,840 B
    __shared__ float bls[3 * 128], gs[128], bs[128];
    const int tid = threadIdx.x;
    if (tid < 128) { gs[tid] = g0[tid]; bs[tid] = b0[tid]; }
    for (int i = tid; i < 384; i += 256) bls[i] = bl[i];

    const int lane = tid & 63, wid = tid >> 6;
    const int lr = lane & 15, lg = lane >> 4;
    const int ntiles = C1n / 16;                  // 9375
    int rt = blockIdx.x * 4 + wid;
    const bool valid = (rt < ntiles);
    if (rt > ntiles - 1) rt = ntiles - 1;         // clamp for loads only
    const int r0 = rt * 16;

    // x fragments: t-invariant, load once
    bf16x8 xa[2];
    xa[0] = frag8(&x[(size_t)(r0 + lr) * 64 + 0  + 8 * lg]);
    xa[1] = frag8(&x[(size_t)(r0 + lr) * 64 + 32 + 8 * lg]);

    f32x4 hacc[8];
#pragma unroll
    for (int n = 0; n < 8; n++) hacc[n] = 0;

    for (int t = 0; t < 3; t++) {
        __syncthreads();                          // Wt reuse protection
        const bf16x8* src = (const bf16x8*)(W1_c + (size_t)t * 128 * PAD128);
        for (int i = tid; i < 128 * PAD128 / 8; i += 256)    // 2240 16B copies
            ((bf16x8*)Wt)[i] = src[i];
        __syncthreads();

        const u16* aggT = agg3 + (size_t)t * C1n * 64;
        f32x4 ta[8];
#pragma unroll
        for (int n = 0; n < 8; n++) ta[n] = 0;
#pragma unroll
        for (int ks = 0; ks < 4; ks++) {
            bf16x8 a;
            if (ks < 2)
                a = *(const bf16x8*)&aggT[(size_t)(r0 + lr) * 64 + ks * 32 + 8 * lg];
            else
                a = xa[ks - 2];
#pragma unroll
            for (int n = 0; n < 8; n++) {
                bf16x8 b = *(const bf16x8*)&Wt[(16 * n + lr) * PAD128 + ks * 32 + 8 * lg];
                ta[n] = mfma16(a, b, ta[n]);
            }
        }
        // + bias, row L2 norm (row = 4*lg + j; cols spread over 16 lanes x 8 n-tiles)
        float ss[4] = {0.f, 0.f, 0.f, 0.f};
#pragma unroll
        for (int n = 0; n < 8; n++) {
            const float bb = bls[t * 128 + 16 * n + lr];
#pragma unroll
            for (int j = 0; j < 4; j++) {
                ta[n][j] += bb;
                ss[j] += ta[n][j] * ta[n][j];
            }
        }
#pragma unroll
        for (int j = 0; j < 4; j++)
            ss[j] = 1.f / fmaxf(sqrtf(red16(ss[j])), 1e-12f);
#pragma unroll
        for (int n = 0; n < 8; n++)
#pragma unroll
            for (int j = 0; j < 4; j++) hacc[n][j] += ta[n][j] * ss[j];
    }

    // relu + /3 + LayerNorm over 128 cols
    float mu[4] = {0.f, 0.f, 0.f, 0.f};
#pragma unroll
    for (int n = 0; n < 8; n++)
#pragma unroll
        for (int j = 0; j < 4; j++) {
            float v = fmaxf(hacc[n][j], 0.f) * (1.f / 3.f);
            hacc[n][j] = v; mu[j] += v;
        }
#pragma unroll
    for (int j = 0; j < 4; j++) mu[j] = red16(mu[j]) * (1.f / 128.f);
    float var[4] = {0.f, 0.f, 0.f, 0.f};
#pragma unroll
    for (int n = 0; n < 8; n++)
#pragma unroll
        for (int j = 0; j < 4; j++) {
            float d = hacc[n][j] - mu[j]; var[j] += d * d;
        }
#pragma unroll
    for (int j = 0; j < 4; j++) var[j] = rsqrtf(red16(var[j]) * (1.f / 128.f) + 1e-5f);

    if (valid) {
#pragma unroll
        for (int n = 0; n < 8; n++) {
            const float g = gs[16 * n + lr], bb = bs[16 * n + lr];
#pragma unroll
            for (int j = 0; j < 4; j++) {
                float o = (hacc[n][j] - mu[j]) * var[j] * g + bb;
                h1[(size_t)(r0 + 4 * lg + j) * 128 + 16 * n + lr] = f2bf(o);
            }
        }
    }
}

// ---------------- gather layer2: agg2_t[r] = mean of h1[src] (bf16 -> bf16) ----------------
__global__ __launch_bounds__(256) void k_gath2(const int* __restrict__ rp,
    const int* __restrict__ el, const u16* __restrict__ h1,
    u16* __restrict__ agg2t)
{
    const int gid = blockIdx.x * 4 + (threadIdx.x >> 6);
    if (gid >= C0n) return;
    const int lane = threadIdx.x & 63;
    const int b = rp[gid];
    const int e = (gid == C0n - 1) ? E0n : rp[gid + 1];
    float s0 = 0.f, s1 = 0.f;
    for (int i = b; i < e; i++) {
        const int sr = el[i];
        unsigned u = *(const unsigned*)&h1[(size_t)sr * 128 + lane * 2];
        s0 += bf2f((u16)(u & 0xffffu));
        s1 += bf2f((u16)(u >> 16));
    }
    const float inv = 1.f / (float)max(e - b, 1);
    unsigned o = (unsigned)f2bf(s0 * inv) | ((unsigned)f2bf(s1 * inv) << 16);
    *(unsigned*)&agg2t[(size_t)gid * 128 + lane * 2] = o;
}

// ------- fused layer2: per-(t,hh) staging = vector memcpy from W2_c; valid-guard -------
__global__ __launch_bounds__(256) void k_out2f(const u16* __restrict__ agg2,
    const u16* __restrict__ h1, const u16* __restrict__ W2_c,
    const float* __restrict__ bl2,
    const float* __restrict__ g1, const float* __restrict__ b1,
    float* __restrict__ out)
{
    __shared__ __align__(16) u16 Wt[128 * PAD128];
    __shared__ float bsm[128], gs[128], bs[128];
    const int tid = threadIdx.x;
    if (tid < 128) {
        gs[tid] = g1[tid]; bs[tid] = b1[tid];
        bsm[tid] = bl2[tid] + bl2[128 + tid] + bl2[256 + tid];
    }
    const int lane = tid & 63, wid = tid >> 6;
    const int lr = lane & 15, lg = lane >> 4;
    const int ntiles = C0n / 16;                  // 3125
    int rt = blockIdx.x * 4 + wid;
    const bool valid = (rt < ntiles);
    if (rt > ntiles - 1) rt = ntiles - 1;         // clamp for loads only
    const int r0 = rt * 16;

    // h1 fragments: t-invariant, load once (bf16 direct)
    bf16x8 ha[4];
#pragma unroll
    for (int ks = 0; ks < 4; ks++)
        ha[ks] = *(const bf16x8*)&h1[(size_t)(r0 + lr) * 128 + ks * 32 + 8 * lg];

    f32x4 acc[8];
#pragma unroll
    for (int n = 0; n < 8; n++) acc[n] = 0;

    for (int t = 0; t < 3; t++) {
        for (int hh = 0; hh < 2; hh++) {
            __syncthreads();                      // Wt reuse protection
            const bf16x8* src = (const bf16x8*)(W2_c +
                (size_t)((hh ? 3 : 0) + t) * 128 * PAD128);
            for (int i = tid; i < 128 * PAD128 / 8; i += 256)
                ((bf16x8*)Wt)[i] = src[i];
            __syncthreads();
#pragma unroll
            for (int ks = 0; ks < 4; ks++) {
                bf16x8 a;
                if (hh == 0)
                    a = *(const bf16x8*)&agg2[(size_t)t * C0n * 128 +
                                              (size_t)(r0 + lr) * 128 + ks * 32 + 8 * lg];
                else
                    a = ha[ks];
#pragma unroll
                for (int n = 0; n < 8; n++) {
                    bf16x8 b = *(const bf16x8*)&Wt[(16 * n + lr) * PAD128 + ks * 32 + 8 * lg];
                    acc[n] = mfma16(a, b, acc[n]);
                }
            }
        }
    }

    // (acc + Σbias)/3, relu, LN
    float mu[4] = {0.f, 0.f, 0.f, 0.f};
#pragma unroll
    for (int n = 0; n < 8; n++) {
        const float bb = bsm[16 * n + lr];
#pragma unroll
        for (int j = 0; j < 4; j++) {
            float v = fmaxf((acc[n][j] + bb) * (1.f / 3.f), 0.f);
            acc[n][j] = v; mu[j] += v;
        }
    }
#pragma unroll
    for (int j = 0; j < 4; j++) mu[j] = red16(mu[j]) * (1.f / 128.f);
    float var[4] = {0.f, 0.f, 0.f, 0.f};
#pragma unroll
    for (int n = 0; n < 8; n++)
#pragma unroll
        for (int j = 0; j < 4; j++) {
            float d = acc[n][j] - mu[j]; var[j] += d * d;
        }
#pragma unroll
    for (int j = 0; j < 4; j++) var[j] = rsqrtf(red16(var[j]) * (1.f / 128.f) + 1e-5f);

    if (valid) {
#pragma unroll
        for (int n = 0; n < 8; n++) {
            const float g = gs[16 * n + lr], bb = bs[16 * n + lr];
#pragma unroll
            for (int j = 0; j < 4; j++) {
                float o = (acc[n][j] - mu[j]) * var[j] * g + bb;
                out[(size_t)(r0 + 4 * lg + j) * 128 + 16 * n + lr] = o;
            }
        }
    }
}

extern "C" void kernel_launch(void* const* d_in, const int* in_sizes, int n_in,
                              void* d_out, int out_size, void* d_ws, size_t ws_size,
                              hipStream_t stream)
{
    const float* x   = (const float*)d_in[0];
    const int*   ei[3] = { (const int*)d_in[1], (const int*)d_in[2], (const int*)d_in[3] };
    const float* Wp  = (const float*)d_in[6];
    const float* bp  = (const float*)d_in[7];
    const float* Wl  = (const float*)d_in[8];
    const float* bl  = (const float*)d_in[9];
    const float* Wr  = (const float*)d_in[10];
    const float* Wl2 = (const float*)d_in[11];
    const float* bl2 = (const float*)d_in[12];
    const float* Wr2 = (const float*)d_in[13];
    const float* g0  = (const float*)d_in[14];
    const float* b0  = (const float*)d_in[15];
    const float* g1  = (const float*)d_in[16];
    const float* b1  = (const float*)d_in[17];

    // ---- workspace layout (bytes) ----
    char* W = (char*)d_ws;
    u16*   agg3 = (u16*)(W + 0);             // 3*C1*64 bf16 = 57,600,000
    u16*   xp3  = (u16*)(W + 57600000);      // 3*C2*64 bf16 = 115,200,000 -> 172,800,000
    u16*   h1   = (u16*)(W + 57600000);      // C1*128 bf16 = 38,400,000 (overlays xp3 t=0)
    int*   rp1  = (int*)(W + 172800000);     // 3*C1*4 = 1,800,000
    int*   fill1= (int*)(W + 174600000);     // 1,800,000 (dead after layer-1 k_fill)
    int*   bsum = (int*)(W + 176400000);     // 4 KiB
    int*   el1  = (int*)(W + 176404096);     // 3*NE*4 = 10,800,000 -> ends 187,204,096
    // weight caches overlay fill1 (dead after layer-1 k_fill); total 351,744 B < 1.8MB
    u16*   Wp_c = (u16*)(W + 174600000);     // 3*64*76*2  = 29,184
    u16*   W1_c = (u16*)(W + 174629184);     // 3*128*140*2 = 107,520
    u16*   W2_c = (u16*)(W + 174736704);     // 6*128*140*2 = 215,040 -> ends 174,951,744
    // layer-2 overlays: agg3 dead after out1f
    u16*   agg2 = (u16*)(W + 0);             // 3*C0*128 bf16 = 38,400,000
    int*   rp2  = (int*)(W + 38400000);      // 600,000
    int*   fill2= (int*)(W + 39000000);      // 600,000
    int*   el2  = (int*)(W + 39600000);      // 3*E0*4 = 3,600,000 -> ends 43,200,000

    const int nb1 = (C1n + 2047) / 2048;  // 74
    const int nb2 = (C0n + 2047) / 2048;  // 25

    // ---- CSR layer 1 (dst over full edge list, nV=C1) ----
    hipMemsetAsync(rp1, 0, 2 * 3 * (size_t)C1n * 4, stream);   // rp1 + fill1
    k_hist<<<dim3((NEn + 255) / 256, 3), 256, 0, stream>>>(
        ei[0] + NEn, ei[1] + NEn, ei[2] + NEn, rp1, NEn, C1n);
    k_scan_a<<<dim3(nb1, 3), 256, 0, stream>>>(rp1, C1n, bsum, nb1);
    k_scan_b<<<dim3(1, 3), 256, 0, stream>>>(bsum, nb1);
    k_scan_c<<<dim3(nb1, 3), 256, 0, stream>>>(rp1, C1n, bsum, nb1);
    k_fill<<<dim3((NEn + 255) / 256, 3), 256, 0, stream>>>(
        ei[0], ei[1], ei[2], ei[0] + NEn, ei[1] + NEn, ei[2] + NEn,
        rp1, fill1, el1, NEn, C1n);

    // ---- weight pre-conversion (after k_fill frees fill1 region) ----
    k_wconv<<<176, 256, 0, stream>>>(Wp, Wl, Wr, Wl2, Wr2, Wp_c, W1_c, W2_c);

    // ---- layer 1: one proj for all t, gathers, fused out+LN ----
    k_projm3<<<(C2n / 16 + 3) / 4, 256, 0, stream>>>(x, Wp_c, bp, xp3);
    for (int t = 0; t < 3; t++)
        k_gath1<<<(C1n + 3) / 4, 256, 0, stream>>>(rp1 + (size_t)t * C1n,
                                                   el1 + (size_t)t * NEn,
                                                   xp3 + (size_t)t * C2n * 64,
                                                   agg3 + (size_t)t * C1n * 64);
    k_out1f<<<(C1n / 16 + 3) / 4, 256, 0, stream>>>(agg3, x, W1_c, bl, g0, b0, h1);

    // ---- CSR layer 2 (first E0 edges, nV=C0) ----
    hipMemsetAsync(rp2, 0, 2 * 3 * (size_t)C0n * 4, stream);   // rp2 + fill2
    k_hist<<<dim3((E0n + 255) / 256, 3), 256, 0, stream>>>(
        ei[0] + NEn, ei[1] + NEn, ei[2] + NEn, rp2, E0n, C0n);
    k_scan_a<<<dim3(nb2, 3), 256, 0, stream>>>(rp2, C0n, bsum, nb2);
    k_scan_b<<<dim3(1, 3), 256, 0, stream>>>(bsum, nb2);
    k_scan_c<<<dim3(nb2, 3), 256, 0, stream>>>(rp2, C0n, bsum, nb2);
    k_fill<<<dim3((E0n + 255) / 256, 3), 256, 0, stream>>>(
        ei[0], ei[1], ei[2], ei[0] + NEn, ei[1] + NEn, ei[2] + NEn,
        rp2, fill2, el2, E0n, C0n);

    // ---- layer 2: gathers, fused out+LN -> d_out ----
    for (int t = 0; t < 3; t++)
        k_gath2<<<(C0n + 3) / 4, 256, 0, stream>>>(rp2 + (size_t)t * C0n,
                                                   el2 + (size_t)t * E0n, h1,
                                                   agg2 + (size_t)t * C0n * 128);
    k_out2f<<<(C0n / 16 + 3) / 4, 256, 0, stream>>>(agg2, h1, W2_c, bl2, g1, b1,
                                                    (float*)d_out);
}

// Round 14
// 776.440 us; speedup vs baseline: 2.6169x; 1.1238x over previous
//
#include <hip/hip_runtime.h>

#define C0n 50000
#define C1n 150000
#define C2n 300000
#define E0n 300000
#define E1n 600000
#define NEn (E0n + E1n)
#define PAD64 76     // 64-col weight tile stride (u16): 152B = 38 words, 38%32=6 -> ~2-way
#define PAD128 140   // 128-col weight tile stride (u16): 280B = 70 words, 70%32=6 -> ~2-way

typedef float  v4f    __attribute__((ext_vector_type(4)));
typedef float  v2f    __attribute__((ext_vector_type(2)));
typedef float  f32x4  __attribute__((ext_vector_type(4)));
typedef short  bf16x8 __attribute__((ext_vector_type(8)));
typedef int    i32x4  __attribute__((ext_vector_type(4)));
typedef unsigned short u16;

__device__ __forceinline__ u16 f2bf(float f){
    unsigned u = __builtin_bit_cast(unsigned, f);
    u += 0x7FFFu + ((u >> 16) & 1u);          // RNE
    return (u16)(u >> 16);
}
__device__ __forceinline__ float bf2f(u16 h){
    unsigned u = ((unsigned)h) << 16;
    return __builtin_bit_cast(float, u);
}
__device__ __forceinline__ f32x4 mfma16(bf16x8 a, bf16x8 b, f32x4 c){
    return __builtin_amdgcn_mfma_f32_16x16x32_bf16(a, b, c, 0, 0, 0);
}
__device__ __forceinline__ float red16(float v){
    v += __shfl_xor(v, 1); v += __shfl_xor(v, 2);
    v += __shfl_xor(v, 4); v += __shfl_xor(v, 8);
    return v;
}
// 8 consecutive f32 -> bf16x8 fragment (16B-aligned source)
__device__ __forceinline__ bf16x8 frag8(const float* __restrict__ p){
    v4f a = *(const v4f*)p, b = *(const v4f*)(p + 4);
    bf16x8 r;
    r[0] = (short)f2bf(a[0]); r[1] = (short)f2bf(a[1]);
    r[2] = (short)f2bf(a[2]); r[3] = (short)f2bf(a[3]);
    r[4] = (short)f2bf(b[0]); r[5] = (short)f2bf(b[1]);
    r[6] = (short)f2bf(b[2]); r[7] = (short)f2bf(b[3]);
    return r;
}

// ------- one-shot: pre-transpose + pre-pad + pre-bf16 all weights into caches -------
__global__ __launch_bounds__(256) void k_wconv(const float* __restrict__ Wp,
    const float* __restrict__ Wl, const float* __restrict__ Wr,
    const float* __restrict__ Wl2, const float* __restrict__ Wr2,
    u16* __restrict__ Wp_c, u16* __restrict__ W1_c, u16* __restrict__ W2_c)
{
    const int i0 = blockIdx.x * 256 + threadIdx.x;
    const int stride = gridDim.x * 256;
    for (int idx = i0; idx < 3 * 64 * PAD64; idx += stride) {
        int t = idx / (64 * PAD64), r = idx % (64 * PAD64);
        int c = r / PAD64, k = r % PAD64;
        Wp_c[idx] = (k < 64) ? f2bf(Wp[t * 4096 + k * 64 + c]) : (u16)0;
    }
    for (int idx = i0; idx < 3 * 128 * PAD128; idx += stride) {
        int t = idx / (128 * PAD128), r = idx % (128 * PAD128);
        int c = r / PAD128, k = r % PAD128;
        u16 v = 0;
        if (k < 64)       v = f2bf(Wl[t * 8192 + k * 128 + c]);
        else if (k < 128) v = f2bf(Wr[t * 8192 + (k - 64) * 128 + c]);
        W1_c[idx] = v;
    }
    for (int idx = i0; idx < 6 * 128 * PAD128; idx += stride) {
        int m = idx / (128 * PAD128), r = idx % (128 * PAD128);
        int t = m % 3;
        const float* W = (m >= 3) ? Wr2 : Wl2;
        int c = r / PAD128, k = r % PAD128;
        W2_c[idx] = (k < 128) ? f2bf(W[t * 16384 + k * 128 + c]) : (u16)0;
    }
}

// ------- xp_t = relu(x @ Wp[t] + bp[t]) for ALL t (staging = vector memcpy) -------
__global__ __launch_bounds__(256) void k_projm3(const float* __restrict__ x,
    const u16* __restrict__ Wp_c, const float* __restrict__ bp,
    u16* __restrict__ xp3)
{
    __shared__ __align__(16) u16 Wt[3 * 64 * PAD64];   // 29,184 B
    __shared__ float bps[3 * 64];
    const int tid = threadIdx.x;
    for (int i = tid; i < 192; i += 256) bps[i] = bp[i];
    for (int i = tid; i < 3 * 64 * PAD64 / 8; i += 256)
        ((bf16x8*)Wt)[i] = ((const bf16x8*)Wp_c)[i];
    __syncthreads();

    const int lane = tid & 63, wid = tid >> 6;
    const int lr = lane & 15, lg = lane >> 4;
    const int ntiles = C2n / 16;                  // 18750
    int rt = blockIdx.x * 4 + wid;
    const bool valid = (rt < ntiles);
    if (rt > ntiles - 1) rt = ntiles - 1;         // clamp for loads only
    const int r0 = rt * 16;

    bf16x8 xa[2];
    xa[0] = frag8(&x[(size_t)(r0 + lr) * 64 + 0  + 8 * lg]);
    xa[1] = frag8(&x[(size_t)(r0 + lr) * 64 + 32 + 8 * lg]);

    for (int t = 0; t < 3; t++) {
        f32x4 acc[4];
#pragma unroll
        for (int n = 0; n < 4; n++) acc[n] = 0;
#pragma unroll
        for (int ks = 0; ks < 2; ks++) {
#pragma unroll
            for (int n = 0; n < 4; n++) {
                bf16x8 b = *(const bf16x8*)&Wt[t * 64 * PAD64 + (16 * n + lr) * PAD64 + ks * 32 + 8 * lg];
                acc[n] = mfma16(xa[ks], b, acc[n]);
            }
        }
        if (valid) {
            u16* xp = xp3 + (size_t)t * C2n * 64;
#pragma unroll
            for (int n = 0; n < 4; n++) {
                const float bb = bps[t * 64 + 16 * n + lr];
#pragma unroll
                for (int j = 0; j < 4; j++)
                    xp[(size_t)(r0 + 4 * lg + j) * 64 + 16 * n + lr] =
                        f2bf(fmaxf(acc[n][j] + bb, 0.f));
            }
        }
    }
}

// ---------------- CSR build: histogram ----------------
__global__ __launch_bounds__(256) void k_hist(const int* __restrict__ d0,
    const int* __restrict__ d1, const int* __restrict__ d2,
    int* __restrict__ deg, int nE, int nV)
{
    const int e = blockIdx.x * 256 + threadIdx.x;
    if (e >= nE) return;
    const int y = blockIdx.y;
    const int* d = (y == 0) ? d0 : (y == 1) ? d1 : d2;
    atomicAdd(&deg[(size_t)y * nV + d[e]], 1);
}

// ---------------- CSR build: exclusive scan ----------------
__global__ __launch_bounds__(256) void k_scan_a(int* __restrict__ a, int n,
    int* __restrict__ bsum, int nblk)
{
    __shared__ int sd[256];
    const int t = threadIdx.x, y = blockIdx.y;
    int* arr = a + (size_t)y * n;
    const int base = blockIdx.x * 2048 + t * 8;
    int v[8];
#pragma unroll
    for (int j = 0; j < 8; j++) v[j] = (base + j < n) ? arr[base + j] : 0;
    int tot = 0;
#pragma unroll
    for (int j = 0; j < 8; j++) { int tmp = v[j]; v[j] = tot; tot += tmp; }
    sd[t] = tot; __syncthreads();
    for (int off = 1; off < 256; off <<= 1) {
        int xv = (t >= off) ? sd[t - off] : 0;
        __syncthreads();
        sd[t] += xv;
        __syncthreads();
    }
    const int excl = sd[t] - tot;
#pragma unroll
    for (int j = 0; j < 8; j++)
        if (base + j < n) arr[base + j] = excl + v[j];
    if (t == 255) bsum[y * nblk + blockIdx.x] = sd[255];
}

__global__ __launch_bounds__(256) void k_scan_b(int* __restrict__ bsum, int nblk)
{
    __shared__ int sd[256];
    const int t = threadIdx.x, y = blockIdx.y;
    int val = (t < nblk) ? bsum[y * nblk + t] : 0;
    sd[t] = val; __syncthreads();
    for (int off = 1; off < 256; off <<= 1) {
        int xv = (t >= off) ? sd[t - off] : 0;
        __syncthreads();
        sd[t] += xv;
        __syncthreads();
    }
    if (t < nblk) bsum[y * nblk + t] = sd[t] - val;
}

__global__ __launch_bounds__(256) void k_scan_c(int* __restrict__ a, int n,
    const int* __restrict__ bsum, int nblk)
{
    const int t = threadIdx.x, y = blockIdx.y;
    int* arr = a + (size_t)y * n;
    const int base = blockIdx.x * 2048 + t * 8;
    const int add = bsum[y * nblk + blockIdx.x];
#pragma unroll
    for (int j = 0; j < 8; j++)
        if (base + j < n) arr[base + j] += add;
}

// ---------------- copy rp -> fill (vector int4) ----------------
__global__ __launch_bounds__(256) void k_copy4(const int* __restrict__ src,
    int* __restrict__ dst, int n4)
{
    const int i = blockIdx.x * 256 + threadIdx.x;
    if (i < n4) ((i32x4*)dst)[i] = ((const i32x4*)src)[i];
}

// ---------------- CSR build: fill; fill[] pre-initialized to rp[] so the atomic
//                  return value IS the write position (2 random touches, not 3) ----------------
__global__ __launch_bounds__(256) void k_fillp(const int* __restrict__ s0,
    const int* __restrict__ s1, const int* __restrict__ s2,
    const int* __restrict__ d0, const int* __restrict__ d1, const int* __restrict__ d2,
    int* __restrict__ fill, int* __restrict__ el, int nE, int nV)
{
    const int e = blockIdx.x * 256 + threadIdx.x;
    if (e >= nE) return;
    const int y = blockIdx.y;
    const int* s = (y == 0) ? s0 : (y == 1) ? s1 : s2;
    const int* d = (y == 0) ? d0 : (y == 1) ? d1 : d2;
    const int pos = atomicAdd(&fill[(size_t)y * nV + d[e]], 1);
    el[(size_t)y * nE + pos] = s[e];
}

// ------- gather layer1 (all t via blockIdx.y): half-wave per row + 2x unroll (4-deep MLP) -------
__global__ __launch_bounds__(256) void k_gath1(const int* __restrict__ rp1,
    const int* __restrict__ el1, const u16* __restrict__ xp3,
    u16* __restrict__ agg3)
{
    const int t = blockIdx.y;
    const int* rp = rp1 + (size_t)t * C1n;
    const int* el = el1 + (size_t)t * NEn;
    const u16* xp = xp3 + (size_t)t * C2n * 64;
    u16* aggt = agg3 + (size_t)t * C1n * 64;

    const int gid = blockIdx.x * 4 + (threadIdx.x >> 6);
    if (gid >= C1n) return;
    const int half = (threadIdx.x >> 5) & 1, l32 = threadIdx.x & 31;
    const int b = rp[gid];
    const int e = (gid == C1n - 1) ? NEn : rp[gid + 1];

    float s0 = 0.f, s1 = 0.f;
    int i = b + half;
    for (; i + 2 < e; i += 4) {               // two rows in flight per half-wave
        const int sr0 = el[i], sr1 = el[i + 2];
        unsigned u0 = *(const unsigned*)&xp[(size_t)sr0 * 64 + l32 * 2];
        unsigned u1 = *(const unsigned*)&xp[(size_t)sr1 * 64 + l32 * 2];
        s0 += bf2f((u16)(u0 & 0xffffu)) + bf2f((u16)(u1 & 0xffffu));
        s1 += bf2f((u16)(u0 >> 16)) + bf2f((u16)(u1 >> 16));
    }
    for (; i < e; i += 2) {
        const int sr = el[i];
        unsigned u = *(const unsigned*)&xp[(size_t)sr * 64 + l32 * 2];
        s0 += bf2f((u16)(u & 0xffffu));
        s1 += bf2f((u16)(u >> 16));
    }
    s0 += __shfl_xor(s0, 32);
    s1 += __shfl_xor(s1, 32);
    if (half == 0) {
        const float inv = 1.f / (float)max(e - b, 1);
        unsigned o = (unsigned)f2bf(s0 * inv) | ((unsigned)f2bf(s1 * inv) << 16);
        *(unsigned*)&aggt[(size_t)gid * 64 + l32 * 2] = o;
    }
}

// ------- fused layer1: staging = vector memcpy from W1_c (r13-validated) -------
__global__ __launch_bounds__(256) void k_out1f(const u16* __restrict__ agg3,
    const float* __restrict__ x, const u16* __restrict__ W1_c,
    const float* __restrict__ bl,
    const float* __restrict__ g0, const float* __restrict__ b0,
    u16* __restrict__ h1)
{
    __shared__ __align__(16) u16 Wt[128 * PAD128];   // 35,840 B
    __shared__ float bls[3 * 128], gs[128], bs[128];
    const int tid = threadIdx.x;
    if (tid < 128) { gs[tid] = g0[tid]; bs[tid] = b0[tid]; }
    for (int i = tid; i < 384; i += 256) bls[i] = bl[i];

    const int lane = tid & 63, wid = tid >> 6;
    const int lr = lane & 15, lg = lane >> 4;
    const int ntiles = C1n / 16;                  // 9375
    int rt = blockIdx.x * 4 + wid;
    const bool valid = (rt < ntiles);
    if (rt > ntiles - 1) rt = ntiles - 1;         // clamp for loads only
    const int r0 = rt * 16;

    bf16x8 xa[2];
    xa[0] = frag8(&x[(size_t)(r0 + lr) * 64 + 0  + 8 * lg]);
    xa[1] = frag8(&x[(size_t)(r0 + lr) * 64 + 32 + 8 * lg]);

    f32x4 hacc[8];
#pragma unroll
    for (int n = 0; n < 8; n++) hacc[n] = 0;

    for (int t = 0; t < 3; t++) {
        __syncthreads();                          // Wt reuse protection
        const bf16x8* src = (const bf16x8*)(W1_c + (size_t)t * 128 * PAD128);
        for (int i = tid; i < 128 * PAD128 / 8; i += 256)
            ((bf16x8*)Wt)[i] = src[i];
        __syncthreads();

        const u16* aggT = agg3 + (size_t)t * C1n * 64;
        f32x4 ta[8];
#pragma unroll
        for (int n = 0; n < 8; n++) ta[n] = 0;
#pragma unroll
        for (int ks = 0; ks < 4; ks++) {
            bf16x8 a;
            if (ks < 2)
                a = *(const bf16x8*)&aggT[(size_t)(r0 + lr) * 64 + ks * 32 + 8 * lg];
            else
                a = xa[ks - 2];
#pragma unroll
            for (int n = 0; n < 8; n++) {
                bf16x8 b = *(const bf16x8*)&Wt[(16 * n + lr) * PAD128 + ks * 32 + 8 * lg];
                ta[n] = mfma16(a, b, ta[n]);
            }
        }
        float ss[4] = {0.f, 0.f, 0.f, 0.f};
#pragma unroll
        for (int n = 0; n < 8; n++) {
            const float bb = bls[t * 128 + 16 * n + lr];
#pragma unroll
            for (int j = 0; j < 4; j++) {
                ta[n][j] += bb;
                ss[j] += ta[n][j] * ta[n][j];
            }
        }
#pragma unroll
        for (int j = 0; j < 4; j++)
            ss[j] = 1.f / fmaxf(sqrtf(red16(ss[j])), 1e-12f);
#pragma unroll
        for (int n = 0; n < 8; n++)
#pragma unroll
            for (int j = 0; j < 4; j++) hacc[n][j] += ta[n][j] * ss[j];
    }

    float mu[4] = {0.f, 0.f, 0.f, 0.f};
#pragma unroll
    for (int n = 0; n < 8; n++)
#pragma unroll
        for (int j = 0; j < 4; j++) {
            float v = fmaxf(hacc[n][j], 0.f) * (1.f / 3.f);
            hacc[n][j] = v; mu[j] += v;
        }
#pragma unroll
    for (int j = 0; j < 4; j++) mu[j] = red16(mu[j]) * (1.f / 128.f);
    float var[4] = {0.f, 0.f, 0.f, 0.f};
#pragma unroll
    for (int n = 0; n < 8; n++)
#pragma unroll
        for (int j = 0; j < 4; j++) {
            float d = hacc[n][j] - mu[j]; var[j] += d * d;
        }
#pragma unroll
    for (int j = 0; j < 4; j++) var[j] = rsqrtf(red16(var[j]) * (1.f / 128.f) + 1e-5f);

    if (valid) {
#pragma unroll
        for (int n = 0; n < 8; n++) {
            const float g = gs[16 * n + lr], bb = bs[16 * n + lr];
#pragma unroll
            for (int j = 0; j < 4; j++) {
                float o = (hacc[n][j] - mu[j]) * var[j] * g + bb;
                h1[(size_t)(r0 + 4 * lg + j) * 128 + 16 * n + lr] = f2bf(o);
            }
        }
    }
}

// ------- gather layer2 (all t via blockIdx.y): 2x edge unroll (2 rows in flight) -------
__global__ __launch_bounds__(256) void k_gath2(const int* __restrict__ rp2,
    const int* __restrict__ el2, const u16* __restrict__ h1,
    u16* __restrict__ agg2)
{
    const int t = blockIdx.y;
    const int* rp = rp2 + (size_t)t * C0n;
    const int* el = el2 + (size_t)t * E0n;
    u16* agg2t = agg2 + (size_t)t * C0n * 128;

    const int gid = blockIdx.x * 4 + (threadIdx.x >> 6);
    if (gid >= C0n) return;
    const int lane = threadIdx.x & 63;
    const int b = rp[gid];
    const int e = (gid == C0n - 1) ? E0n : rp[gid + 1];
    float s0 = 0.f, s1 = 0.f;
    int i = b;
    for (; i + 1 < e; i += 2) {
        const int sr0 = el[i], sr1 = el[i + 1];
        unsigned u0 = *(const unsigned*)&h1[(size_t)sr0 * 128 + lane * 2];
        unsigned u1 = *(const unsigned*)&h1[(size_t)sr1 * 128 + lane * 2];
        s0 += bf2f((u16)(u0 & 0xffffu)) + bf2f((u16)(u1 & 0xffffu));
        s1 += bf2f((u16)(u0 >> 16)) + bf2f((u16)(u1 >> 16));
    }
    if (i < e) {
        const int sr = el[i];
        unsigned u = *(const unsigned*)&h1[(size_t)sr * 128 + lane * 2];
        s0 += bf2f((u16)(u & 0xffffu));
        s1 += bf2f((u16)(u >> 16));
    }
    const float inv = 1.f / (float)max(e - b, 1);
    unsigned o = (unsigned)f2bf(s0 * inv) | ((unsigned)f2bf(s1 * inv) << 16);
    *(unsigned*)&agg2t[(size_t)gid * 128 + lane * 2] = o;
}

// ------- fused layer2: staging = vector memcpy from W2_c (r13-validated) -------
__global__ __launch_bounds__(256) void k_out2f(const u16* __restrict__ agg2,
    const u16* __restrict__ h1, const u16* __restrict__ W2_c,
    const float* __restrict__ bl2,
    const float* __restrict__ g1, const float* __restrict__ b1,
    float* __restrict__ out)
{
    __shared__ __align__(16) u16 Wt[128 * PAD128];
    __shared__ float bsm[128], gs[128], bs[128];
    const int tid = threadIdx.x;
    if (tid < 128) {
        gs[tid] = g1[tid]; bs[tid] = b1[tid];
        bsm[tid] = bl2[tid] + bl2[128 + tid] + bl2[256 + tid];
    }
    const int lane = tid & 63, wid = tid >> 6;
    const int lr = lane & 15, lg = lane >> 4;
    const int ntiles = C0n / 16;                  // 3125
    int rt = blockIdx.x * 4 + wid;
    const bool valid = (rt < ntiles);
    if (rt > ntiles - 1) rt = ntiles - 1;         // clamp for loads only
    const int r0 = rt * 16;

    bf16x8 ha[4];
#pragma unroll
    for (int ks = 0; ks < 4; ks++)
        ha[ks] = *(const bf16x8*)&h1[(size_t)(r0 + lr) * 128 + ks * 32 + 8 * lg];

    f32x4 acc[8];
#pragma unroll
    for (int n = 0; n < 8; n++) acc[n] = 0;

    for (int t = 0; t < 3; t++) {
        for (int hh = 0; hh < 2; hh++) {
            __syncthreads();                      // Wt reuse protection
            const bf16x8* src = (const bf16x8*)(W2_c +
                (size_t)((hh ? 3 : 0) + t) * 128 * PAD128);
            for (int i = tid; i < 128 * PAD128 / 8; i += 256)
                ((bf16x8*)Wt)[i] = src[i];
            __syncthreads();
#pragma unroll
            for (int ks = 0; ks < 4; ks++) {
                bf16x8 a;
                if (hh == 0)
                    a = *(const bf16x8*)&agg2[(size_t)t * C0n * 128 +
                                              (size_t)(r0 + lr) * 128 + ks * 32 + 8 * lg];
                else
                    a = ha[ks];
#pragma unroll
                for (int n = 0; n < 8; n++) {
                    bf16x8 b = *(const bf16x8*)&Wt[(16 * n + lr) * PAD128 + ks * 32 + 8 * lg];
                    acc[n] = mfma16(a, b, acc[n]);
                }
            }
        }
    }

    float mu[4] = {0.f, 0.f, 0.f, 0.f};
#pragma unroll
    for (int n = 0; n < 8; n++) {
        const float bb = bsm[16 * n + lr];
#pragma unroll
        for (int j = 0; j < 4; j++) {
            float v = fmaxf((acc[n][j] + bb) * (1.f / 3.f), 0.f);
            acc[n][j] = v; mu[j] += v;
        }
    }
#pragma unroll
    for (int j = 0; j < 4; j++) mu[j] = red16(mu[j]) * (1.f / 128.f);
    float var[4] = {0.f, 0.f, 0.f, 0.f};
#pragma unroll
    for (int n = 0; n < 8; n++)
#pragma unroll
        for (int j = 0; j < 4; j++) {
            float d = acc[n][j] - mu[j]; var[j] += d * d;
        }
#pragma unroll
    for (int j = 0; j < 4; j++) var[j] = rsqrtf(red16(var[j]) * (1.f / 128.f) + 1e-5f);

    if (valid) {
#pragma unroll
        for (int n = 0; n < 8; n++) {
            const float g = gs[16 * n + lr], bb = bs[16 * n + lr];
#pragma unroll
            for (int j = 0; j < 4; j++) {
                float o = (acc[n][j] - mu[j]) * var[j] * g + bb;
                out[(size_t)(r0 + 4 * lg + j) * 128 + 16 * n + lr] = o;
            }
        }
    }
}

extern "C" void kernel_launch(void* const* d_in, const int* in_sizes, int n_in,
                              void* d_out, int out_size, void* d_ws, size_t ws_size,
                              hipStream_t stream)
{
    const float* x   = (const float*)d_in[0];
    const int*   ei[3] = { (const int*)d_in[1], (const int*)d_in[2], (const int*)d_in[3] };
    const float* Wp  = (const float*)d_in[6];
    const float* bp  = (const float*)d_in[7];
    const float* Wl  = (const float*)d_in[8];
    const float* bl  = (const float*)d_in[9];
    const float* Wr  = (const float*)d_in[10];
    const float* Wl2 = (const float*)d_in[11];
    const float* bl2 = (const float*)d_in[12];
    const float* Wr2 = (const float*)d_in[13];
    const float* g0  = (const float*)d_in[14];
    const float* b0  = (const float*)d_in[15];
    const float* g1  = (const float*)d_in[16];
    const float* b1  = (const float*)d_in[17];

    // ---- workspace layout (bytes) ----
    char* W = (char*)d_ws;
    u16*   agg3 = (u16*)(W + 0);             // 3*C1*64 bf16 = 57,600,000
    u16*   xp3  = (u16*)(W + 57600000);      // 3*C2*64 bf16 = 115,200,000 -> 172,800,000
    u16*   h1   = (u16*)(W + 57600000);      // C1*128 bf16 = 38,400,000 (overlays xp3 t=0)
    int*   rp1  = (int*)(W + 172800000);     // 3*C1*4 = 1,800,000
    int*   fill1= (int*)(W + 174600000);     // 1,800,000 (dead after layer-1 fill)
    int*   bsum = (int*)(W + 176400000);     // 4 KiB
    int*   el1  = (int*)(W + 176404096);     // 3*NE*4 = 10,800,000 -> ends 187,204,096
    // weight caches overlay fill1 (dead after layer-1 fill); total 351,744 B < 1.8MB
    u16*   Wp_c = (u16*)(W + 174600000);     // 29,184
    u16*   W1_c = (u16*)(W + 174629184);     // 107,520
    u16*   W2_c = (u16*)(W + 174736704);     // 215,040 -> ends 174,951,744
    // layer-2 overlays: agg3 dead after out1f
    u16*   agg2 = (u16*)(W + 0);             // 3*C0*128 bf16 = 38,400,000
    int*   rp2  = (int*)(W + 38400000);      // 600,000
    int*   fill2= (int*)(W + 39000000);      // 600,000
    int*   el2  = (int*)(W + 39600000);      // 3,600,000 -> ends 43,200,000

    const int nb1 = (C1n + 2047) / 2048;  // 74
    const int nb2 = (C0n + 2047) / 2048;  // 25

    // ---- CSR layer 1 (dst over full edge list, nV=C1) ----
    hipMemsetAsync(rp1, 0, 3 * (size_t)C1n * 4, stream);
    k_hist<<<dim3((NEn + 255) / 256, 3), 256, 0, stream>>>(
        ei[0] + NEn, ei[1] + NEn, ei[2] + NEn, rp1, NEn, C1n);
    k_scan_a<<<dim3(nb1, 3), 256, 0, stream>>>(rp1, C1n, bsum, nb1);
    k_scan_b<<<dim3(1, 3), 256, 0, stream>>>(bsum, nb1);
    k_scan_c<<<dim3(nb1, 3), 256, 0, stream>>>(rp1, C1n, bsum, nb1);
    k_copy4<<<(3 * C1n / 4 + 255) / 256, 256, 0, stream>>>(rp1, fill1, 3 * C1n / 4);
    k_fillp<<<dim3((NEn + 255) / 256, 3), 256, 0, stream>>>(
        ei[0], ei[1], ei[2], ei[0] + NEn, ei[1] + NEn, ei[2] + NEn,
        fill1, el1, NEn, C1n);

    // ---- weight pre-conversion (after fill frees fill1 region) ----
    k_wconv<<<176, 256, 0, stream>>>(Wp, Wl, Wr, Wl2, Wr2, Wp_c, W1_c, W2_c);

    // ---- layer 1: one proj for all t, merged gathers, fused out+LN ----
    k_projm3<<<(C2n / 16 + 3) / 4, 256, 0, stream>>>(x, Wp_c, bp, xp3);
    k_gath1<<<dim3((C1n + 3) / 4, 3), 256, 0, stream>>>(rp1, el1, xp3, agg3);
    k_out1f<<<(C1n / 16 + 3) / 4, 256, 0, stream>>>(agg3, x, W1_c, bl, g0, b0, h1);

    // ---- CSR layer 2 (first E0 edges, nV=C0) ----
    hipMemsetAsync(rp2, 0, 3 * (size_t)C0n * 4, stream);
    k_hist<<<dim3((E0n + 255) / 256, 3), 256, 0, stream>>>(
        ei[0] + NEn, ei[1] + NEn, ei[2] + NEn, rp2, E0n, C0n);
    k_scan_a<<<dim3(nb2, 3), 256, 0, stream>>>(rp2, C0n, bsum, nb2);
    k_scan_b<<<dim3(1, 3), 256, 0, stream>>>(bsum, nb2);
    k_scan_c<<<dim3(nb2, 3), 256, 0, stream>>>(rp2, C0n, bsum, nb2);
    k_copy4<<<(3 * C0n / 4 + 255) / 256, 256, 0, stream>>>(rp2, fill2, 3 * C0n / 4);
    k_fillp<<<dim3((E0n + 255) / 256, 3), 256, 0, stream>>>(
        ei[0], ei[1], ei[2], ei[0] + NEn, ei[1] + NEn, ei[2] + NEn,
        fill2, el2, E0n, C0n);

    // ---- layer 2: merged gathers, fused out+LN -> d_out ----
    k_gath2<<<dim3((C0n + 3) / 4, 3), 256, 0, stream>>>(rp2, el2, h1, agg2);
    k_out2f<<<(C0n / 16 + 3) / 4, 256, 0, stream>>>(agg2, h1, W2_c, bl2, g1, b1,
                                                    (float*)d_out);
}

// Round 15
// 691.318 us; speedup vs baseline: 2.9392x; 1.1231x over previous
//
#include <hip/hip_runtime.h>

#define C0n 50000
#define C1n 150000
#define C2n 300000
#define E0n 300000
#define E1n 600000
#define NEn (E0n + E1n)
#define PAD64 76     // 64-col weight tile stride (u16): 152B = 38 words, 38%32=6 -> ~2-way
#define PAD128 140   // 128-col weight tile stride (u16): 280B = 70 words, 70%32=6 -> ~2-way

typedef float  v4f    __attribute__((ext_vector_type(4)));
typedef float  v2f    __attribute__((ext_vector_type(2)));
typedef float  f32x4  __attribute__((ext_vector_type(4)));
typedef short  bf16x8 __attribute__((ext_vector_type(8)));
typedef unsigned short u16;

__device__ __forceinline__ u16 f2bf(float f){
    unsigned u = __builtin_bit_cast(unsigned, f);
    u += 0x7FFFu + ((u >> 16) & 1u);          // RNE
    return (u16)(u >> 16);
}
__device__ __forceinline__ float bf2f(u16 h){
    unsigned u = ((unsigned)h) << 16;
    return __builtin_bit_cast(float, u);
}
__device__ __forceinline__ f32x4 mfma16(bf16x8 a, bf16x8 b, f32x4 c){
    return __builtin_amdgcn_mfma_f32_16x16x32_bf16(a, b, c, 0, 0, 0);
}
__device__ __forceinline__ float red16(float v){
    v += __shfl_xor(v, 1); v += __shfl_xor(v, 2);
    v += __shfl_xor(v, 4); v += __shfl_xor(v, 8);
    return v;
}
// 8 consecutive f32 -> bf16x8 fragment (16B-aligned source)
__device__ __forceinline__ bf16x8 frag8(const float* __restrict__ p){
    v4f a = *(const v4f*)p, b = *(const v4f*)(p + 4);
    bf16x8 r;
    r[0] = (short)f2bf(a[0]); r[1] = (short)f2bf(a[1]);
    r[2] = (short)f2bf(a[2]); r[3] = (short)f2bf(a[3]);
    r[4] = (short)f2bf(b[0]); r[5] = (short)f2bf(b[1]);
    r[6] = (short)f2bf(b[2]); r[7] = (short)f2bf(b[3]);
    return r;
}

// ------- one-shot: pre-transpose + pre-pad + pre-bf16 all weights into caches -------
__global__ __launch_bounds__(256) void k_wconv(const float* __restrict__ Wp,
    const float* __restrict__ Wl, const float* __restrict__ Wr,
    const float* __restrict__ Wl2, const float* __restrict__ Wr2,
    u16* __restrict__ Wp_c, u16* __restrict__ W1_c, u16* __restrict__ W2_c)
{
    const int i0 = blockIdx.x * 256 + threadIdx.x;
    const int stride = gridDim.x * 256;
    for (int idx = i0; idx < 3 * 64 * PAD64; idx += stride) {
        int t = idx / (64 * PAD64), r = idx % (64 * PAD64);
        int c = r / PAD64, k = r % PAD64;
        Wp_c[idx] = (k < 64) ? f2bf(Wp[t * 4096 + k * 64 + c]) : (u16)0;
    }
    for (int idx = i0; idx < 3 * 128 * PAD128; idx += stride) {
        int t = idx / (128 * PAD128), r = idx % (128 * PAD128);
        int c = r / PAD128, k = r % PAD128;
        u16 v = 0;
        if (k < 64)       v = f2bf(Wl[t * 8192 + k * 128 + c]);
        else if (k < 128) v = f2bf(Wr[t * 8192 + (k - 64) * 128 + c]);
        W1_c[idx] = v;
    }
    for (int idx = i0; idx < 6 * 128 * PAD128; idx += stride) {
        int m = idx / (128 * PAD128), r = idx % (128 * PAD128);
        int t = m % 3;
        const float* W = (m >= 3) ? Wr2 : Wl2;
        int c = r / PAD128, k = r % PAD128;
        W2_c[idx] = (k < 128) ? f2bf(W[t * 16384 + k * 128 + c]) : (u16)0;
    }
}

// ------- xp_t = relu(x @ Wp[t] + bp[t]) for ALL t (staging = vector memcpy) -------
__global__ __launch_bounds__(256) void k_projm3(const float* __restrict__ x,
    const u16* __restrict__ Wp_c, const float* __restrict__ bp,
    u16* __restrict__ xp3)
{
    __shared__ __align__(16) u16 Wt[3 * 64 * PAD64];   // 29,184 B
    __shared__ float bps[3 * 64];
    const int tid = threadIdx.x;
    for (int i = tid; i < 192; i += 256) bps[i] = bp[i];
    for (int i = tid; i < 3 * 64 * PAD64 / 8; i += 256)
        ((bf16x8*)Wt)[i] = ((const bf16x8*)Wp_c)[i];
    __syncthreads();

    const int lane = tid & 63, wid = tid >> 6;
    const int lr = lane & 15, lg = lane >> 4;
    const int ntiles = C2n / 16;                  // 18750
    int rt = blockIdx.x * 4 + wid;
    const bool valid = (rt < ntiles);
    if (rt > ntiles - 1) rt = ntiles - 1;         // clamp for loads only
    const int r0 = rt * 16;

    bf16x8 xa[2];
    xa[0] = frag8(&x[(size_t)(r0 + lr) * 64 + 0  + 8 * lg]);
    xa[1] = frag8(&x[(size_t)(r0 + lr) * 64 + 32 + 8 * lg]);

    for (int t = 0; t < 3; t++) {
        f32x4 acc[4];
#pragma unroll
        for (int n = 0; n < 4; n++) acc[n] = 0;
#pragma unroll
        for (int ks = 0; ks < 2; ks++) {
#pragma unroll
            for (int n = 0; n < 4; n++) {
                bf16x8 b = *(const bf16x8*)&Wt[t * 64 * PAD64 + (16 * n + lr) * PAD64 + ks * 32 + 8 * lg];
                acc[n] = mfma16(xa[ks], b, acc[n]);
            }
        }
        if (valid) {
            u16* xp = xp3 + (size_t)t * C2n * 64;
#pragma unroll
            for (int n = 0; n < 4; n++) {
                const float bb = bps[t * 64 + 16 * n + lr];
#pragma unroll
                for (int j = 0; j < 4; j++)
                    xp[(size_t)(r0 + 4 * lg + j) * 64 + 16 * n + lr] =
                        f2bf(fmaxf(acc[n][j] + bb, 0.f));
            }
        }
    }
}

// ---------------- CSR build: histogram ----------------
__global__ __launch_bounds__(256) void k_hist(const int* __restrict__ d0,
    const int* __restrict__ d1, const int* __restrict__ d2,
    int* __restrict__ deg, int nE, int nV)
{
    const int e = blockIdx.x * 256 + threadIdx.x;
    if (e >= nE) return;
    const int y = blockIdx.y;
    const int* d = (y == 0) ? d0 : (y == 1) ? d1 : d2;
    atomicAdd(&deg[(size_t)y * nV + d[e]], 1);
}

// ---------------- CSR build: exclusive scan ----------------
__global__ __launch_bounds__(256) void k_scan_a(int* __restrict__ a, int n,
    int* __restrict__ bsum, int nblk)
{
    __shared__ int sd[256];
    const int t = threadIdx.x, y = blockIdx.y;
    int* arr = a + (size_t)y * n;
    const int base = blockIdx.x * 2048 + t * 8;
    int v[8];
#pragma unroll
    for (int j = 0; j < 8; j++) v[j] = (base + j < n) ? arr[base + j] : 0;
    int tot = 0;
#pragma unroll
    for (int j = 0; j < 8; j++) { int tmp = v[j]; v[j] = tot; tot += tmp; }
    sd[t] = tot; __syncthreads();
    for (int off = 1; off < 256; off <<= 1) {
        int xv = (t >= off) ? sd[t - off] : 0;
        __syncthreads();
        sd[t] += xv;
        __syncthreads();
    }
    const int excl = sd[t] - tot;
#pragma unroll
    for (int j = 0; j < 8; j++)
        if (base + j < n) arr[base + j] = excl + v[j];
    if (t == 255) bsum[y * nblk + blockIdx.x] = sd[255];
}

__global__ __launch_bounds__(256) void k_scan_b(int* __restrict__ bsum, int nblk)
{
    __shared__ int sd[256];
    const int t = threadIdx.x, y = blockIdx.y;
    int val = (t < nblk) ? bsum[y * nblk + t] : 0;
    sd[t] = val; __syncthreads();
    for (int off = 1; off < 256; off <<= 1) {
        int xv = (t >= off) ? sd[t - off] : 0;
        __syncthreads();
        sd[t] += xv;
        __syncthreads();
    }
    if (t < nblk) bsum[y * nblk + t] = sd[t] - val;
}

__global__ __launch_bounds__(256) void k_scan_c(int* __restrict__ a, int n,
    const int* __restrict__ bsum, int nblk)
{
    const int t = threadIdx.x, y = blockIdx.y;
    int* arr = a + (size_t)y * n;
    const int base = blockIdx.x * 2048 + t * 8;
    const int add = bsum[y * nblk + blockIdx.x];
#pragma unroll
    for (int j = 0; j < 8; j++)
        if (base + j < n) arr[base + j] += add;
}

// ---------------- CSR build: fill (r13-validated, fastest measured variant) ----------------
__global__ __launch_bounds__(256) void k_fill(const int* __restrict__ s0,
    const int* __restrict__ s1, const int* __restrict__ s2,
    const int* __restrict__ d0, const int* __restrict__ d1, const int* __restrict__ d2,
    const int* __restrict__ rp, int* __restrict__ fill, int* __restrict__ el,
    int nE, int nV)
{
    const int e = blockIdx.x * 256 + threadIdx.x;
    if (e >= nE) return;
    const int y = blockIdx.y;
    const int* s = (y == 0) ? s0 : (y == 1) ? s1 : s2;
    const int* d = (y == 0) ? d0 : (y == 1) ? d1 : d2;
    const int dd = d[e];
    const int pos = rp[(size_t)y * nV + dd] + atomicAdd(&fill[(size_t)y * nV + dd], 1);
    el[(size_t)y * nE + pos] = s[e];
}

// ------- gather layer1 (all t via blockIdx.y): half-wave per row + 2x unroll (r14-validated) -------
__global__ __launch_bounds__(256) void k_gath1(const int* __restrict__ rp1,
    const int* __restrict__ el1, const u16* __restrict__ xp3,
    u16* __restrict__ agg3)
{
    const int t = blockIdx.y;
    const int* rp = rp1 + (size_t)t * C1n;
    const int* el = el1 + (size_t)t * NEn;
    const u16* xp = xp3 + (size_t)t * C2n * 64;
    u16* aggt = agg3 + (size_t)t * C1n * 64;

    const int gid = blockIdx.x * 4 + (threadIdx.x >> 6);
    if (gid >= C1n) return;
    const int half = (threadIdx.x >> 5) & 1, l32 = threadIdx.x & 31;
    const int b = rp[gid];
    const int e = (gid == C1n - 1) ? NEn : rp[gid + 1];

    float s0 = 0.f, s1 = 0.f;
    int i = b + half;
    for (; i + 2 < e; i += 4) {               // two rows in flight per half-wave
        const int sr0 = el[i], sr1 = el[i + 2];
        unsigned u0 = *(const unsigned*)&xp[(size_t)sr0 * 64 + l32 * 2];
        unsigned u1 = *(const unsigned*)&xp[(size_t)sr1 * 64 + l32 * 2];
        s0 += bf2f((u16)(u0 & 0xffffu)) + bf2f((u16)(u1 & 0xffffu));
        s1 += bf2f((u16)(u0 >> 16)) + bf2f((u16)(u1 >> 16));
    }
    for (; i < e; i += 2) {
        const int sr = el[i];
        unsigned u = *(const unsigned*)&xp[(size_t)sr * 64 + l32 * 2];
        s0 += bf2f((u16)(u & 0xffffu));
        s1 += bf2f((u16)(u >> 16));
    }
    s0 += __shfl_xor(s0, 32);
    s1 += __shfl_xor(s1, 32);
    if (half == 0) {
        const float inv = 1.f / (float)max(e - b, 1);
        unsigned o = (unsigned)f2bf(s0 * inv) | ((unsigned)f2bf(s1 * inv) << 16);
        *(unsigned*)&aggt[(size_t)gid * 64 + l32 * 2] = o;
    }
}

// ------- fused layer1: staging = vector memcpy from W1_c (r13-validated) -------
__global__ __launch_bounds__(256) void k_out1f(const u16* __restrict__ agg3,
    const float* __restrict__ x, const u16* __restrict__ W1_c,
    const float* __restrict__ bl,
    const float* __restrict__ g0, const float* __restrict__ b0,
    u16* __restrict__ h1)
{
    __shared__ __align__(16) u16 Wt[128 * PAD128];   // 35,840 B
    __shared__ float bls[3 * 128], gs[128], bs[128];
    const int tid = threadIdx.x;
    if (tid < 128) { gs[tid] = g0[tid]; bs[tid] = b0[tid]; }
    for (int i = tid; i < 384; i += 256) bls[i] = bl[i];

    const int lane = tid & 63, wid = tid >> 6;
    const int lr = lane & 15, lg = lane >> 4;
    const int ntiles = C1n / 16;                  // 9375
    int rt = blockIdx.x * 4 + wid;
    const bool valid = (rt < ntiles);
    if (rt > ntiles - 1) rt = ntiles - 1;         // clamp for loads only
    const int r0 = rt * 16;

    bf16x8 xa[2];
    xa[0] = frag8(&x[(size_t)(r0 + lr) * 64 + 0  + 8 * lg]);
    xa[1] = frag8(&x[(size_t)(r0 + lr) * 64 + 32 + 8 * lg]);

    f32x4 hacc[8];
#pragma unroll
    for (int n = 0; n < 8; n++) hacc[n] = 0;

    for (int t = 0; t < 3; t++) {
        __syncthreads();                          // Wt reuse protection
        const bf16x8* src = (const bf16x8*)(W1_c + (size_t)t * 128 * PAD128);
        for (int i = tid; i < 128 * PAD128 / 8; i += 256)
            ((bf16x8*)Wt)[i] = src[i];
        __syncthreads();

        const u16* aggT = agg3 + (size_t)t * C1n * 64;
        f32x4 ta[8];
#pragma unroll
        for (int n = 0; n < 8; n++) ta[n] = 0;
#pragma unroll
        for (int ks = 0; ks < 4; ks++) {
            bf16x8 a;
            if (ks < 2)
                a = *(const bf16x8*)&aggT[(size_t)(r0 + lr) * 64 + ks * 32 + 8 * lg];
            else
                a = xa[ks - 2];
#pragma unroll
            for (int n = 0; n < 8; n++) {
                bf16x8 b = *(const bf16x8*)&Wt[(16 * n + lr) * PAD128 + ks * 32 + 8 * lg];
                ta[n] = mfma16(a, b, ta[n]);
            }
        }
        float ss[4] = {0.f, 0.f, 0.f, 0.f};
#pragma unroll
        for (int n = 0; n < 8; n++) {
            const float bb = bls[t * 128 + 16 * n + lr];
#pragma unroll
            for (int j = 0; j < 4; j++) {
                ta[n][j] += bb;
                ss[j] += ta[n][j] * ta[n][j];
            }
        }
#pragma unroll
        for (int j = 0; j < 4; j++)
            ss[j] = 1.f / fmaxf(sqrtf(red16(ss[j])), 1e-12f);
#pragma unroll
        for (int n = 0; n < 8; n++)
#pragma unroll
            for (int j = 0; j < 4; j++) hacc[n][j] += ta[n][j] * ss[j];
    }

    float mu[4] = {0.f, 0.f, 0.f, 0.f};
#pragma unroll
    for (int n = 0; n < 8; n++)
#pragma unroll
        for (int j = 0; j < 4; j++) {
            float v = fmaxf(hacc[n][j], 0.f) * (1.f / 3.f);
            hacc[n][j] = v; mu[j] += v;
        }
#pragma unroll
    for (int j = 0; j < 4; j++) mu[j] = red16(mu[j]) * (1.f / 128.f);
    float var[4] = {0.f, 0.f, 0.f, 0.f};
#pragma unroll
    for (int n = 0; n < 8; n++)
#pragma unroll
        for (int j = 0; j < 4; j++) {
            float d = hacc[n][j] - mu[j]; var[j] += d * d;
        }
#pragma unroll
    for (int j = 0; j < 4; j++) var[j] = rsqrtf(red16(var[j]) * (1.f / 128.f) + 1e-5f);

    if (valid) {
#pragma unroll
        for (int n = 0; n < 8; n++) {
            const float g = gs[16 * n + lr], bb = bs[16 * n + lr];
#pragma unroll
            for (int j = 0; j < 4; j++) {
                float o = (hacc[n][j] - mu[j]) * var[j] * g + bb;
                h1[(size_t)(r0 + 4 * lg + j) * 128 + 16 * n + lr] = f2bf(o);
            }
        }
    }
}

// ------- gather layer2 (all t via blockIdx.y): 2x edge unroll (r14-validated) -------
__global__ __launch_bounds__(256) void k_gath2(const int* __restrict__ rp2,
    const int* __restrict__ el2, const u16* __restrict__ h1,
    u16* __restrict__ agg2)
{
    const int t = blockIdx.y;
    const int* rp = rp2 + (size_t)t * C0n;
    const int* el = el2 + (size_t)t * E0n;
    u16* agg2t = agg2 + (size_t)t * C0n * 128;

    const int gid = blockIdx.x * 4 + (threadIdx.x >> 6);
    if (gid >= C0n) return;
    const int lane = threadIdx.x & 63;
    const int b = rp[gid];
    const int e = (gid == C0n - 1) ? E0n : rp[gid + 1];
    float s0 = 0.f, s1 = 0.f;
    int i = b;
    for (; i + 1 < e; i += 2) {
        const int sr0 = el[i], sr1 = el[i + 1];
        unsigned u0 = *(const unsigned*)&h1[(size_t)sr0 * 128 + lane * 2];
        unsigned u1 = *(const unsigned*)&h1[(size_t)sr1 * 128 + lane * 2];
        s0 += bf2f((u16)(u0 & 0xffffu)) + bf2f((u16)(u1 & 0xffffu));
        s1 += bf2f((u16)(u0 >> 16)) + bf2f((u16)(u1 >> 16));
    }
    if (i < e) {
        const int sr = el[i];
        unsigned u = *(const unsigned*)&h1[(size_t)sr * 128 + lane * 2];
        s0 += bf2f((u16)(u & 0xffffu));
        s1 += bf2f((u16)(u >> 16));
    }
    const float inv = 1.f / (float)max(e - b, 1);
    unsigned o = (unsigned)f2bf(s0 * inv) | ((unsigned)f2bf(s1 * inv) << 16);
    *(unsigned*)&agg2t[(size_t)gid * 128 + lane * 2] = o;
}

// ------- fused layer2: staging = vector memcpy from W2_c (r13-validated) -------
__global__ __launch_bounds__(256) void k_out2f(const u16* __restrict__ agg2,
    const u16* __restrict__ h1, const u16* __restrict__ W2_c,
    const float* __restrict__ bl2,
    const float* __restrict__ g1, const float* __restrict__ b1,
    float* __restrict__ out)
{
    __shared__ __align__(16) u16 Wt[128 * PAD128];
    __shared__ float bsm[128], gs[128], bs[128];
    const int tid = threadIdx.x;
    if (tid < 128) {
        gs[tid] = g1[tid]; bs[tid] = b1[tid];
        bsm[tid] = bl2[tid] + bl2[128 + tid] + bl2[256 + tid];
    }
    const int lane = tid & 63, wid = tid >> 6;
    const int lr = lane & 15, lg = lane >> 4;
    const int ntiles = C0n / 16;                  // 3125
    int rt = blockIdx.x * 4 + wid;
    const bool valid = (rt < ntiles);
    if (rt > ntiles - 1) rt = ntiles - 1;         // clamp for loads only
    const int r0 = rt * 16;

    bf16x8 ha[4];
#pragma unroll
    for (int ks = 0; ks < 4; ks++)
        ha[ks] = *(const bf16x8*)&h1[(size_t)(r0 + lr) * 128 + ks * 32 + 8 * lg];

    f32x4 acc[8];
#pragma unroll
    for (int n = 0; n < 8; n++) acc[n] = 0;

    for (int t = 0; t < 3; t++) {
        for (int hh = 0; hh < 2; hh++) {
            __syncthreads();                      // Wt reuse protection
            const bf16x8* src = (const bf16x8*)(W2_c +
                (size_t)((hh ? 3 : 0) + t) * 128 * PAD128);
            for (int i = tid; i < 128 * PAD128 / 8; i += 256)
                ((bf16x8*)Wt)[i] = src[i];
            __syncthreads();
#pragma unroll
            for (int ks = 0; ks < 4; ks++) {
                bf16x8 a;
                if (hh == 0)
                    a = *(const bf16x8*)&agg2[(size_t)t * C0n * 128 +
                                              (size_t)(r0 + lr) * 128 + ks * 32 + 8 * lg];
                else
                    a = ha[ks];
#pragma unroll
                for (int n = 0; n < 8; n++) {
                    bf16x8 b = *(const bf16x8*)&Wt[(16 * n + lr) * PAD128 + ks * 32 + 8 * lg];
                    acc[n] = mfma16(a, b, acc[n]);
                }
            }
        }
    }

    float mu[4] = {0.f, 0.f, 0.f, 0.f};
#pragma unroll
    for (int n = 0; n < 8; n++) {
        const float bb = bsm[16 * n + lr];
#pragma unroll
        for (int j = 0; j < 4; j++) {
            float v = fmaxf((acc[n][j] + bb) * (1.f / 3.f), 0.f);
            acc[n][j] = v; mu[j] += v;
        }
    }
#pragma unroll
    for (int j = 0; j < 4; j++) mu[j] = red16(mu[j]) * (1.f / 128.f);
    float var[4] = {0.f, 0.f, 0.f, 0.f};
#pragma unroll
    for (int n = 0; n < 8; n++)
#pragma unroll
        for (int j = 0; j < 4; j++) {
            float d = acc[n][j] - mu[j]; var[j] += d * d;
        }
#pragma unroll
    for (int j = 0; j < 4; j++) var[j] = rsqrtf(red16(var[j]) * (1.f / 128.f) + 1e-5f);

    if (valid) {
#pragma unroll
        for (int n = 0; n < 8; n++) {
            const float g = gs[16 * n + lr], bb = bs[16 * n + lr];
#pragma unroll
            for (int j = 0; j < 4; j++) {
                float o = (acc[n][j] - mu[j]) * var[j] * g + bb;
                out[(size_t)(r0 + 4 * lg + j) * 128 + 16 * n + lr] = o;
            }
        }
    }
}

extern "C" void kernel_launch(void* const* d_in, const int* in_sizes, int n_in,
                              void* d_out, int out_size, void* d_ws, size_t ws_size,
                              hipStream_t stream)
{
    const float* x   = (const float*)d_in[0];
    const int*   ei[3] = { (const int*)d_in[1], (const int*)d_in[2], (const int*)d_in[3] };
    const float* Wp  = (const float*)d_in[6];
    const float* bp  = (const float*)d_in[7];
    const float* Wl  = (const float*)d_in[8];
    const float* bl  = (const float*)d_in[9];
    const float* Wr  = (const float*)d_in[10];
    const float* Wl2 = (const float*)d_in[11];
    const float* bl2 = (const float*)d_in[12];
    const float* Wr2 = (const float*)d_in[13];
    const float* g0  = (const float*)d_in[14];
    const float* b0  = (const float*)d_in[15];
    const float* g1  = (const float*)d_in[16];
    const float* b1  = (const float*)d_in[17];

    // ---- workspace layout (bytes) ----
    char* W = (char*)d_ws;
    u16*   agg3 = (u16*)(W + 0);             // 3*C1*64 bf16 = 57,600,000
    u16*   xp3  = (u16*)(W + 57600000);      // 3*C2*64 bf16 = 115,200,000 -> 172,800,000
    u16*   h1   = (u16*)(W + 57600000);      // C1*128 bf16 = 38,400,000 (overlays xp3 t=0)
    int*   rp1  = (int*)(W + 172800000);     // 3*C1*4 = 1,800,000
    int*   fill1= (int*)(W + 174600000);     // 1,800,000 (dead after layer-1 fill)
    int*   bsum = (int*)(W + 176400000);     // 4 KiB
    int*   el1  = (int*)(W + 176404096);     // 3*NE*4 = 10,800,000 -> ends 187,204,096
    // weight caches overlay fill1 (dead after layer-1 fill); total 351,744 B < 1.8MB
    u16*   Wp_c = (u16*)(W + 174600000);     // 29,184
    u16*   W1_c = (u16*)(W + 174629184);     // 107,520
    u16*   W2_c = (u16*)(W + 174736704);     // 215,040 -> ends 174,951,744
    // layer-2 overlays: agg3 dead after out1f
    u16*   agg2 = (u16*)(W + 0);             // 3*C0*128 bf16 = 38,400,000
    int*   rp2  = (int*)(W + 38400000);      // 600,000
    int*   fill2= (int*)(W + 39000000);      // 600,000
    int*   el2  = (int*)(W + 39600000);      // 3,600,000 -> ends 43,200,000

    const int nb1 = (C1n + 2047) / 2048;  // 74
    const int nb2 = (C0n + 2047) / 2048;  // 25

    // ---- CSR layer 1 (dst over full edge list, nV=C1) ----
    hipMemsetAsync(rp1, 0, 2 * 3 * (size_t)C1n * 4, stream);   // rp1 + fill1
    k_hist<<<dim3((NEn + 255) / 256, 3), 256, 0, stream>>>(
        ei[0] + NEn, ei[1] + NEn, ei[2] + NEn, rp1, NEn, C1n);
    k_scan_a<<<dim3(nb1, 3), 256, 0, stream>>>(rp1, C1n, bsum, nb1);
    k_scan_b<<<dim3(1, 3), 256, 0, stream>>>(bsum, nb1);
    k_scan_c<<<dim3(nb1, 3), 256, 0, stream>>>(rp1, C1n, bsum, nb1);
    k_fill<<<dim3((NEn + 255) / 256, 3), 256, 0, stream>>>(
        ei[0], ei[1], ei[2], ei[0] + NEn, ei[1] + NEn, ei[2] + NEn,
        rp1, fill1, el1, NEn, C1n);

    // ---- weight pre-conversion (after fill frees fill1 region) ----
    k_wconv<<<176, 256, 0, stream>>>(Wp, Wl, Wr, Wl2, Wr2, Wp_c, W1_c, W2_c);

    // ---- layer 1: one proj for all t, merged gathers, fused out+LN ----
    k_projm3<<<(C2n / 16 + 3) / 4, 256, 0, stream>>>(x, Wp_c, bp, xp3);
    k_gath1<<<dim3((C1n + 3) / 4, 3), 256, 0, stream>>>(rp1, el1, xp3, agg3);
    k_out1f<<<(C1n / 16 + 3) / 4, 256, 0, stream>>>(agg3, x, W1_c, bl, g0, b0, h1);

    // ---- CSR layer 2 (first E0 edges, nV=C0) ----
    hipMemsetAsync(rp2, 0, 2 * 3 * (size_t)C0n * 4, stream);   // rp2 + fill2
    k_hist<<<dim3((E0n + 255) / 256, 3), 256, 0, stream>>>(
        ei[0] + NEn, ei[1] + NEn, ei[2] + NEn, rp2, E0n, C0n);
    k_scan_a<<<dim3(nb2, 3), 256, 0, stream>>>(rp2, C0n, bsum, nb2);
    k_scan_b<<<dim3(1, 3), 256, 0, stream>>>(bsum, nb2);
    k_scan_c<<<dim3(nb2, 3), 256, 0, stream>>>(rp2, C0n, bsum, nb2);
    k_fill<<<dim3((E0n + 255) / 256, 3), 256, 0, stream>>>(
        ei[0], ei[1], ei[2], ei[0] + NEn, ei[1] + NEn, ei[2] + NEn,
        rp2, fill2, el2, E0n, C0n);

    // ---- layer 2: merged gathers, fused out+LN -> d_out ----
    k_gath2<<<dim3((C0n + 3) / 4, 3), 256, 0, stream>>>(rp2, el2, h1, agg2);
    k_out2f<<<(C0n / 16 + 3) / 4, 256, 0, stream>>>(agg2, h1, W2_c, bl2, g1, b1,
                                                    (float*)d_out);
}

// Round 16
// 609.104 us; speedup vs baseline: 3.3359x; 1.1350x over previous
//
#include <hip/hip_runtime.h>

#define C0n 50000
#define C1n 150000
#define C2n 300000
#define E0n 300000
#define E1n 600000
#define NEn (E0n + E1n)
#define PAD64 76     // 64-col weight tile stride (u16): 152B = 38 words, 38%32=6 -> ~2-way
#define PAD128 140   // 128-col weight tile stride (u16): 280B = 70 words, 70%32=6 -> ~2-way

typedef float  v4f    __attribute__((ext_vector_type(4)));
typedef float  f32x4  __attribute__((ext_vector_type(4)));
typedef short  bf16x8 __attribute__((ext_vector_type(8)));
typedef unsigned short u16;

__device__ __forceinline__ u16 f2bf(float f){
    unsigned u = __builtin_bit_cast(unsigned, f);
    u += 0x7FFFu + ((u >> 16) & 1u);          // RNE
    return (u16)(u >> 16);
}
__device__ __forceinline__ float bf2f(u16 h){
    unsigned u = ((unsigned)h) << 16;
    return __builtin_bit_cast(float, u);
}
__device__ __forceinline__ float bf2f_lo(unsigned u){
    return __builtin_bit_cast(float, u << 16);
}
__device__ __forceinline__ float bf2f_hi(unsigned u){
    return __builtin_bit_cast(float, u & 0xffff0000u);
}
__device__ __forceinline__ f32x4 mfma16(bf16x8 a, bf16x8 b, f32x4 c){
    return __builtin_amdgcn_mfma_f32_16x16x32_bf16(a, b, c, 0, 0, 0);
}
__device__ __forceinline__ float red16(float v){
    v += __shfl_xor(v, 1); v += __shfl_xor(v, 2);
    v += __shfl_xor(v, 4); v += __shfl_xor(v, 8);
    return v;
}
// 8 consecutive f32 -> bf16x8 fragment (16B-aligned source)
__device__ __forceinline__ bf16x8 frag8(const float* __restrict__ p){
    v4f a = *(const v4f*)p, b = *(const v4f*)(p + 4);
    bf16x8 r;
    r[0] = (short)f2bf(a[0]); r[1] = (short)f2bf(a[1]);
    r[2] = (short)f2bf(a[2]); r[3] = (short)f2bf(a[3]);
    r[4] = (short)f2bf(b[0]); r[5] = (short)f2bf(b[1]);
    r[6] = (short)f2bf(b[2]); r[7] = (short)f2bf(b[3]);
    return r;
}

// ------- one-shot: pre-transpose + pre-pad + pre-bf16 all weights into caches -------
__global__ __launch_bounds__(256) void k_wconv(const float* __restrict__ Wp,
    const float* __restrict__ Wl, const float* __restrict__ Wr,
    const float* __restrict__ Wl2, const float* __restrict__ Wr2,
    u16* __restrict__ Wp_c, u16* __restrict__ W1_c, u16* __restrict__ W2_c)
{
    const int i0 = blockIdx.x * 256 + threadIdx.x;
    const int stride = gridDim.x * 256;
    for (int idx = i0; idx < 3 * 64 * PAD64; idx += stride) {
        int t = idx / (64 * PAD64), r = idx % (64 * PAD64);
        int c = r / PAD64, k = r % PAD64;
        Wp_c[idx] = (k < 64) ? f2bf(Wp[t * 4096 + k * 64 + c]) : (u16)0;
    }
    for (int idx = i0; idx < 3 * 128 * PAD128; idx += stride) {
        int t = idx / (128 * PAD128), r = idx % (128 * PAD128);
        int c = r / PAD128, k = r % PAD128;
        u16 v = 0;
        if (k < 64)       v = f2bf(Wl[t * 8192 + k * 128 + c]);
        else if (k < 128) v = f2bf(Wr[t * 8192 + (k - 64) * 128 + c]);
        W1_c[idx] = v;
    }
    for (int idx = i0; idx < 6 * 128 * PAD128; idx += stride) {
        int m = idx / (128 * PAD128), r = idx % (128 * PAD128);
        int t = m % 3;
        const float* W = (m >= 3) ? Wr2 : Wl2;
        int c = r / PAD128, k = r % PAD128;
        W2_c[idx] = (k < 128) ? f2bf(W[t * 16384 + k * 128 + c]) : (u16)0;
    }
}

// ------- xp_t = relu(x @ Wp[t] + bp[t]) for ALL t (r13-validated) -------
__global__ __launch_bounds__(256) void k_projm3(const float* __restrict__ x,
    const u16* __restrict__ Wp_c, const float* __restrict__ bp,
    u16* __restrict__ xp3)
{
    __shared__ __align__(16) u16 Wt[3 * 64 * PAD64];   // 29,184 B
    __shared__ float bps[3 * 64];
    const int tid = threadIdx.x;
    for (int i = tid; i < 192; i += 256) bps[i] = bp[i];
    for (int i = tid; i < 3 * 64 * PAD64 / 8; i += 256)
        ((bf16x8*)Wt)[i] = ((const bf16x8*)Wp_c)[i];
    __syncthreads();

    const int lane = tid & 63, wid = tid >> 6;
    const int lr = lane & 15, lg = lane >> 4;
    const int ntiles = C2n / 16;                  // 18750
    int rt = blockIdx.x * 4 + wid;
    const bool valid = (rt < ntiles);
    if (rt > ntiles - 1) rt = ntiles - 1;         // clamp for loads only
    const int r0 = rt * 16;

    bf16x8 xa[2];
    xa[0] = frag8(&x[(size_t)(r0 + lr) * 64 + 0  + 8 * lg]);
    xa[1] = frag8(&x[(size_t)(r0 + lr) * 64 + 32 + 8 * lg]);

    for (int t = 0; t < 3; t++) {
        f32x4 acc[4];
#pragma unroll
        for (int n = 0; n < 4; n++) acc[n] = 0;
#pragma unroll
        for (int ks = 0; ks < 2; ks++) {
#pragma unroll
            for (int n = 0; n < 4; n++) {
                bf16x8 b = *(const bf16x8*)&Wt[t * 64 * PAD64 + (16 * n + lr) * PAD64 + ks * 32 + 8 * lg];
                acc[n] = mfma16(xa[ks], b, acc[n]);
            }
        }
        if (valid) {
            u16* xp = xp3 + (size_t)t * C2n * 64;
#pragma unroll
            for (int n = 0; n < 4; n++) {
                const float bb = bps[t * 64 + 16 * n + lr];
#pragma unroll
                for (int j = 0; j < 4; j++)
                    xp[(size_t)(r0 + 4 * lg + j) * 64 + 16 * n + lr] =
                        f2bf(fmaxf(acc[n][j] + bb, 0.f));
            }
        }
    }
}

// ================= 6-way CSR build (y<3: layer1 graph y; y>=3: layer2 graph y-3) =================
__global__ __launch_bounds__(256) void k_hist6(const int* __restrict__ d0,
    const int* __restrict__ d1, const int* __restrict__ d2,
    int* __restrict__ rp1, int* __restrict__ rp2)
{
    const int e = blockIdx.x * 256 + threadIdx.x;
    const int y = blockIdx.y;
    const int g = (y < 3) ? y : y - 3;
    const int nE = (y < 3) ? NEn : E0n;
    if (e >= nE) return;
    const int* d = (g == 0) ? d0 : (g == 1) ? d1 : d2;
    int* deg = (y < 3) ? rp1 + (size_t)y * C1n : rp2 + (size_t)(y - 3) * C0n;
    atomicAdd(&deg[d[e]], 1);
}

__global__ __launch_bounds__(256) void k_scan6_a(int* __restrict__ rp1,
    int* __restrict__ rp2, int* __restrict__ bsum, int nblk)
{
    __shared__ int sd[256];
    const int t = threadIdx.x, y = blockIdx.y;
    int* arr = (y < 3) ? rp1 + (size_t)y * C1n : rp2 + (size_t)(y - 3) * C0n;
    const int n = (y < 3) ? C1n : C0n;
    const int base = blockIdx.x * 2048 + t * 8;
    int v[8];
#pragma unroll
    for (int j = 0; j < 8; j++) v[j] = (base + j < n) ? arr[base + j] : 0;
    int tot = 0;
#pragma unroll
    for (int j = 0; j < 8; j++) { int tmp = v[j]; v[j] = tot; tot += tmp; }
    sd[t] = tot; __syncthreads();
    for (int off = 1; off < 256; off <<= 1) {
        int xv = (t >= off) ? sd[t - off] : 0;
        __syncthreads();
        sd[t] += xv;
        __syncthreads();
    }
    const int excl = sd[t] - tot;
#pragma unroll
    for (int j = 0; j < 8; j++)
        if (base + j < n) arr[base + j] = excl + v[j];
    if (t == 255) bsum[y * nblk + blockIdx.x] = sd[255];
}

__global__ __launch_bounds__(256) void k_scan6_b(int* __restrict__ bsum, int nblk)
{
    __shared__ int sd[256];
    const int t = threadIdx.x, y = blockIdx.y;
    int val = (t < nblk) ? bsum[y * nblk + t] : 0;
    sd[t] = val; __syncthreads();
    for (int off = 1; off < 256; off <<= 1) {
        int xv = (t >= off) ? sd[t - off] : 0;
        __syncthreads();
        sd[t] += xv;
        __syncthreads();
    }
    if (t < nblk) bsum[y * nblk + t] = sd[t] - val;
}

__global__ __launch_bounds__(256) void k_scan6_c(int* __restrict__ rp1,
    int* __restrict__ rp2, const int* __restrict__ bsum, int nblk)
{
    const int t = threadIdx.x, y = blockIdx.y;
    int* arr = (y < 3) ? rp1 + (size_t)y * C1n : rp2 + (size_t)(y - 3) * C0n;
    const int n = (y < 3) ? C1n : C0n;
    const int base = blockIdx.x * 2048 + t * 8;
    const int add = bsum[y * nblk + blockIdx.x];
#pragma unroll
    for (int j = 0; j < 8; j++)
        if (base + j < n) arr[base + j] += add;
}

__global__ __launch_bounds__(256) void k_fill6(const int* __restrict__ s0,
    const int* __restrict__ s1, const int* __restrict__ s2,
    const int* __restrict__ d0, const int* __restrict__ d1, const int* __restrict__ d2,
    const int* __restrict__ rp1, const int* __restrict__ rp2,
    int* __restrict__ fill1, int* __restrict__ fill2,
    int* __restrict__ el1, int* __restrict__ el2)
{
    const int e = blockIdx.x * 256 + threadIdx.x;
    const int y = blockIdx.y;
    const int g = (y < 3) ? y : y - 3;
    const int nE = (y < 3) ? NEn : E0n;
    if (e >= nE) return;
    const int* s = (g == 0) ? s0 : (g == 1) ? s1 : s2;
    const int* d = (g == 0) ? d0 : (g == 1) ? d1 : d2;
    const int* rp  = (y < 3) ? rp1  + (size_t)y * C1n : rp2  + (size_t)(y - 3) * C0n;
    int* fill      = (y < 3) ? fill1 + (size_t)y * C1n : fill2 + (size_t)(y - 3) * C0n;
    int* el        = (y < 3) ? el1  + (size_t)y * NEn : el2  + (size_t)(y - 3) * E0n;
    const int dd = d[e];
    const int pos = rp[dd] + atomicAdd(&fill[dd], 1);
    el[pos] = s[e];
}

// ------- gather layer1: 16-lane groups (4 rows/wave), 8B/lane loads, no cross-lane reduce -------
__global__ __launch_bounds__(256) void k_gath1(const int* __restrict__ rp1,
    const int* __restrict__ el1, const u16* __restrict__ xp3,
    u16* __restrict__ agg3)
{
    const int t = blockIdx.y;
    const int* rp = rp1 + (size_t)t * C1n;
    const int* el = el1 + (size_t)t * NEn;
    const u16* xp = xp3 + (size_t)t * C2n * 64;
    u16* aggt = agg3 + (size_t)t * C1n * 64;

    const int gid = blockIdx.x * 16 + (threadIdx.x >> 4);   // C1n % 16 == 0
    const int l16 = threadIdx.x & 15;
    const int b = rp[gid];
    const int e = (gid == C1n - 1) ? NEn : rp[gid + 1];

    float s0 = 0.f, s1 = 0.f, s2 = 0.f, s3 = 0.f;
    int i = b;
    for (; i + 1 < e; i += 2) {                  // 2 rows in flight per group
        const int sr0 = el[i], sr1 = el[i + 1];
        uint2 u0 = *(const uint2*)&xp[(size_t)sr0 * 64 + l16 * 4];
        uint2 u1 = *(const uint2*)&xp[(size_t)sr1 * 64 + l16 * 4];
        s0 += bf2f_lo(u0.x) + bf2f_lo(u1.x);
        s1 += bf2f_hi(u0.x) + bf2f_hi(u1.x);
        s2 += bf2f_lo(u0.y) + bf2f_lo(u1.y);
        s3 += bf2f_hi(u0.y) + bf2f_hi(u1.y);
    }
    if (i < e) {
        uint2 u = *(const uint2*)&xp[(size_t)el[i] * 64 + l16 * 4];
        s0 += bf2f_lo(u.x); s1 += bf2f_hi(u.x);
        s2 += bf2f_lo(u.y); s3 += bf2f_hi(u.y);
    }
    const float inv = 1.f / (float)max(e - b, 1);
    uint2 o;
    o.x = (unsigned)f2bf(s0 * inv) | ((unsigned)f2bf(s1 * inv) << 16);
    o.y = (unsigned)f2bf(s2 * inv) | ((unsigned)f2bf(s3 * inv) << 16);
    *(uint2*)&aggt[(size_t)gid * 64 + l16 * 4] = o;
}

// ------- fused layer1: staging = vector memcpy from W1_c (r13-validated) -------
__global__ __launch_bounds__(256) void k_out1f(const u16* __restrict__ agg3,
    const float* __restrict__ x, const u16* __restrict__ W1_c,
    const float* __restrict__ bl,
    const float* __restrict__ g0, const float* __restrict__ b0,
    u16* __restrict__ h1)
{
    __shared__ __align__(16) u16 Wt[128 * PAD128];   // 35,840 B
    __shared__ float bls[3 * 128], gs[128], bs[128];
    const int tid = threadIdx.x;
    if (tid < 128) { gs[tid] = g0[tid]; bs[tid] = b0[tid]; }
    for (int i = tid; i < 384; i += 256) bls[i] = bl[i];

    const int lane = tid & 63, wid = tid >> 6;
    const int lr = lane & 15, lg = lane >> 4;
    const int ntiles = C1n / 16;                  // 9375
    int rt = blockIdx.x * 4 + wid;
    const bool valid = (rt < ntiles);
    if (rt > ntiles - 1) rt = ntiles - 1;         // clamp for loads only
    const int r0 = rt * 16;

    bf16x8 xa[2];
    xa[0] = frag8(&x[(size_t)(r0 + lr) * 64 + 0  + 8 * lg]);
    xa[1] = frag8(&x[(size_t)(r0 + lr) * 64 + 32 + 8 * lg]);

    f32x4 hacc[8];
#pragma unroll
    for (int n = 0; n < 8; n++) hacc[n] = 0;

    for (int t = 0; t < 3; t++) {
        __syncthreads();                          // Wt reuse protection
        const bf16x8* src = (const bf16x8*)(W1_c + (size_t)t * 128 * PAD128);
        for (int i = tid; i < 128 * PAD128 / 8; i += 256)
            ((bf16x8*)Wt)[i] = src[i];
        __syncthreads();

        const u16* aggT = agg3 + (size_t)t * C1n * 64;
        f32x4 ta[8];
#pragma unroll
        for (int n = 0; n < 8; n++) ta[n] = 0;
#pragma unroll
        for (int ks = 0; ks < 4; ks++) {
            bf16x8 a;
            if (ks < 2)
                a = *(const bf16x8*)&aggT[(size_t)(r0 + lr) * 64 + ks * 32 + 8 * lg];
            else
                a = xa[ks - 2];
#pragma unroll
            for (int n = 0; n < 8; n++) {
                bf16x8 b = *(const bf16x8*)&Wt[(16 * n + lr) * PAD128 + ks * 32 + 8 * lg];
                ta[n] = mfma16(a, b, ta[n]);
            }
        }
        float ss[4] = {0.f, 0.f, 0.f, 0.f};
#pragma unroll
        for (int n = 0; n < 8; n++) {
            const float bb = bls[t * 128 + 16 * n + lr];
#pragma unroll
            for (int j = 0; j < 4; j++) {
                ta[n][j] += bb;
                ss[j] += ta[n][j] * ta[n][j];
            }
        }
#pragma unroll
        for (int j = 0; j < 4; j++)
            ss[j] = 1.f / fmaxf(sqrtf(red16(ss[j])), 1e-12f);
#pragma unroll
        for (int n = 0; n < 8; n++)
#pragma unroll
            for (int j = 0; j < 4; j++) hacc[n][j] += ta[n][j] * ss[j];
    }

    float mu[4] = {0.f, 0.f, 0.f, 0.f};
#pragma unroll
    for (int n = 0; n < 8; n++)
#pragma unroll
        for (int j = 0; j < 4; j++) {
            float v = fmaxf(hacc[n][j], 0.f) * (1.f / 3.f);
            hacc[n][j] = v; mu[j] += v;
        }
#pragma unroll
    for (int j = 0; j < 4; j++) mu[j] = red16(mu[j]) * (1.f / 128.f);
    float var[4] = {0.f, 0.f, 0.f, 0.f};
#pragma unroll
    for (int n = 0; n < 8; n++)
#pragma unroll
        for (int j = 0; j < 4; j++) {
            float d = hacc[n][j] - mu[j]; var[j] += d * d;
        }
#pragma unroll
    for (int j = 0; j < 4; j++) var[j] = rsqrtf(red16(var[j]) * (1.f / 128.f) + 1e-5f);

    if (valid) {
#pragma unroll
        for (int n = 0; n < 8; n++) {
            const float g = gs[16 * n + lr], bb = bs[16 * n + lr];
#pragma unroll
            for (int j = 0; j < 4; j++) {
                float o = (hacc[n][j] - mu[j]) * var[j] * g + bb;
                h1[(size_t)(r0 + 4 * lg + j) * 128 + 16 * n + lr] = f2bf(o);
            }
        }
    }
}

// ------- gather layer2: 16-lane groups (4 rows/wave), 16B/lane loads -------
__global__ __launch_bounds__(256) void k_gath2(const int* __restrict__ rp2,
    const int* __restrict__ el2, const u16* __restrict__ h1,
    u16* __restrict__ agg2)
{
    const int t = blockIdx.y;
    const int* rp = rp2 + (size_t)t * C0n;
    const int* el = el2 + (size_t)t * E0n;
    u16* agg2t = agg2 + (size_t)t * C0n * 128;

    const int gid = blockIdx.x * 16 + (threadIdx.x >> 4);   // C0n % 16 == 0
    const int l16 = threadIdx.x & 15;
    const int b = rp[gid];
    const int e = (gid == C0n - 1) ? E0n : rp[gid + 1];

    float s[8];
#pragma unroll
    for (int j = 0; j < 8; j++) s[j] = 0.f;
    int i = b;
    for (; i + 1 < e; i += 2) {
        const int sr0 = el[i], sr1 = el[i + 1];
        uint4 u0 = *(const uint4*)&h1[(size_t)sr0 * 128 + l16 * 8];
        uint4 u1 = *(const uint4*)&h1[(size_t)sr1 * 128 + l16 * 8];
        s[0] += bf2f_lo(u0.x) + bf2f_lo(u1.x);
        s[1] += bf2f_hi(u0.x) + bf2f_hi(u1.x);
        s[2] += bf2f_lo(u0.y) + bf2f_lo(u1.y);
        s[3] += bf2f_hi(u0.y) + bf2f_hi(u1.y);
        s[4] += bf2f_lo(u0.z) + bf2f_lo(u1.z);
        s[5] += bf2f_hi(u0.z) + bf2f_hi(u1.z);
        s[6] += bf2f_lo(u0.w) + bf2f_lo(u1.w);
        s[7] += bf2f_hi(u0.w) + bf2f_hi(u1.w);
    }
    if (i < e) {
        uint4 u = *(const uint4*)&h1[(size_t)el[i] * 128 + l16 * 8];
        s[0] += bf2f_lo(u.x); s[1] += bf2f_hi(u.x);
        s[2] += bf2f_lo(u.y); s[3] += bf2f_hi(u.y);
        s[4] += bf2f_lo(u.z); s[5] += bf2f_hi(u.z);
        s[6] += bf2f_lo(u.w); s[7] += bf2f_hi(u.w);
    }
    const float inv = 1.f / (float)max(e - b, 1);
    uint4 o;
    o.x = (unsigned)f2bf(s[0] * inv) | ((unsigned)f2bf(s[1] * inv) << 16);
    o.y = (unsigned)f2bf(s[2] * inv) | ((unsigned)f2bf(s[3] * inv) << 16);
    o.z = (unsigned)f2bf(s[4] * inv) | ((unsigned)f2bf(s[5] * inv) << 16);
    o.w = (unsigned)f2bf(s[6] * inv) | ((unsigned)f2bf(s[7] * inv) << 16);
    *(uint4*)&agg2t[(size_t)gid * 128 + l16 * 8] = o;
}

// ------- fused layer2: staging = vector memcpy from W2_c (r13-validated) -------
__global__ __launch_bounds__(256) void k_out2f(const u16* __restrict__ agg2,
    const u16* __restrict__ h1, const u16* __restrict__ W2_c,
    const float* __restrict__ bl2,
    const float* __restrict__ g1, const float* __restrict__ b1,
    float* __restrict__ out)
{
    __shared__ __align__(16) u16 Wt[128 * PAD128];
    __shared__ float bsm[128], gs[128], bs[128];
    const int tid = threadIdx.x;
    if (tid < 128) {
        gs[tid] = g1[tid]; bs[tid] = b1[tid];
        bsm[tid] = bl2[tid] + bl2[128 + tid] + bl2[256 + tid];
    }
    const int lane = tid & 63, wid = tid >> 6;
    const int lr = lane & 15, lg = lane >> 4;
    const int ntiles = C0n / 16;                  // 3125
    int rt = blockIdx.x * 4 + wid;
    const bool valid = (rt < ntiles);
    if (rt > ntiles - 1) rt = ntiles - 1;         // clamp for loads only
    const int r0 = rt * 16;

    bf16x8 ha[4];
#pragma unroll
    for (int ks = 0; ks < 4; ks++)
        ha[ks] = *(const bf16x8*)&h1[(size_t)(r0 + lr) * 128 + ks * 32 + 8 * lg];

    f32x4 acc[8];
#pragma unroll
    for (int n = 0; n < 8; n++) acc[n] = 0;

    for (int t = 0; t < 3; t++) {
        for (int hh = 0; hh < 2; hh++) {
            __syncthreads();                      // Wt reuse protection
            const bf16x8* src = (const bf16x8*)(W2_c +
                (size_t)((hh ? 3 : 0) + t) * 128 * PAD128);
            for (int i = tid; i < 128 * PAD128 / 8; i += 256)
                ((bf16x8*)Wt)[i] = src[i];
            __syncthreads();
#pragma unroll
            for (int ks = 0; ks < 4; ks++) {
                bf16x8 a;
                if (hh == 0)
                    a = *(const bf16x8*)&agg2[(size_t)t * C0n * 128 +
                                              (size_t)(r0 + lr) * 128 + ks * 32 + 8 * lg];
                else
                    a = ha[ks];
#pragma unroll
                for (int n = 0; n < 8; n++) {
                    bf16x8 b = *(const bf16x8*)&Wt[(16 * n + lr) * PAD128 + ks * 32 + 8 * lg];
                    acc[n] = mfma16(a, b, acc[n]);
                }
            }
        }
    }

    float mu[4] = {0.f, 0.f, 0.f, 0.f};
#pragma unroll
    for (int n = 0; n < 8; n++) {
        const float bb = bsm[16 * n + lr];
#pragma unroll
        for (int j = 0; j < 4; j++) {
            float v = fmaxf((acc[n][j] + bb) * (1.f / 3.f), 0.f);
            acc[n][j] = v; mu[j] += v;
        }
    }
#pragma unroll
    for (int j = 0; j < 4; j++) mu[j] = red16(mu[j]) * (1.f / 128.f);
    float var[4] = {0.f, 0.f, 0.f, 0.f};
#pragma unroll
    for (int n = 0; n < 8; n++)
#pragma unroll
        for (int j = 0; j < 4; j++) {
            float d = acc[n][j] - mu[j]; var[j] += d * d;
        }
#pragma unroll
    for (int j = 0; j < 4; j++) var[j] = rsqrtf(red16(var[j]) * (1.f / 128.f) + 1e-5f);

    if (valid) {
#pragma unroll
        for (int n = 0; n < 8; n++) {
            const float g = gs[16 * n + lr], bb = bs[16 * n + lr];
#pragma unroll
            for (int j = 0; j < 4; j++) {
                float o = (acc[n][j] - mu[j]) * var[j] * g + bb;
                out[(size_t)(r0 + 4 * lg + j) * 128 + 16 * n + lr] = o;
            }
        }
    }
}

extern "C" void kernel_launch(void* const* d_in, const int* in_sizes, int n_in,
                              void* d_out, int out_size, void* d_ws, size_t ws_size,
                              hipStream_t stream)
{
    const float* x   = (const float*)d_in[0];
    const int*   ei[3] = { (const int*)d_in[1], (const int*)d_in[2], (const int*)d_in[3] };
    const float* Wp  = (const float*)d_in[6];
    const float* bp  = (const float*)d_in[7];
    const float* Wl  = (const float*)d_in[8];
    const float* bl  = (const float*)d_in[9];
    const float* Wr  = (const float*)d_in[10];
    const float* Wl2 = (const float*)d_in[11];
    const float* bl2 = (const float*)d_in[12];
    const float* Wr2 = (const float*)d_in[13];
    const float* g0  = (const float*)d_in[14];
    const float* b0  = (const float*)d_in[15];
    const float* g1  = (const float*)d_in[16];
    const float* b1  = (const float*)d_in[17];

    // ---- workspace layout (bytes) ----
    char* W = (char*)d_ws;
    u16*   agg3 = (u16*)(W + 0);             // 3*C1*64 bf16 = 57,600,000
    u16*   xp3  = (u16*)(W + 57600000);      // 3*C2*64 bf16 = 115,200,000 -> 172,800,000
    u16*   h1   = (u16*)(W + 57600000);      // C1*128 bf16 = 38,400,000 (overlays xp3 t=0)
    int*   rp1  = (int*)(W + 172800000);     // 3*C1*4 = 1,800,000
    int*   fill1= (int*)(W + 174600000);     // 1,800,000 (dead after fill6)
    int*   bsum = (int*)(W + 176400000);     // 4 KiB (6*74*4 = 1776 B used)
    int*   el1  = (int*)(W + 176404096);     // 3*NE*4 = 10,800,000 -> 187,204,096
    int*   rp2  = (int*)(W + 187204096);     // 3*C0*4 = 600,000
    int*   fill2= (int*)(W + 187804096);     // 600,000
    int*   el2  = (int*)(W + 188404096);     // 3*E0*4 = 3,600,000 -> ends 192,004,096 (r1 proved >=192.6MB)
    // weight caches overlay fill1 (dead after fill6); total 351,744 B < 1.8MB
    u16*   Wp_c = (u16*)(W + 174600000);     // 29,184
    u16*   W1_c = (u16*)(W + 174629184);     // 107,520
    u16*   W2_c = (u16*)(W + 174736704);     // 215,040 -> ends 174,951,744
    // layer-2 overlays: agg3 dead after out1f
    u16*   agg2 = (u16*)(W + 0);             // 3*C0*128 bf16 = 38,400,000

    const int nb = (C1n + 2047) / 2048;  // 74 (covers C0n too; excess blocks no-op)

    // ---- both layers' CSR in 6-way merged kernels ----
    hipMemsetAsync(rp1, 0, 2 * 3 * (size_t)C1n * 4, stream);   // rp1 + fill1
    hipMemsetAsync(rp2, 0, 2 * 3 * (size_t)C0n * 4, stream);   // rp2 + fill2
    k_hist6<<<dim3((NEn + 255) / 256, 6), 256, 0, stream>>>(
        ei[0] + NEn, ei[1] + NEn, ei[2] + NEn, rp1, rp2);
    k_scan6_a<<<dim3(nb, 6), 256, 0, stream>>>(rp1, rp2, bsum, nb);
    k_scan6_b<<<dim3(1, 6), 256, 0, stream>>>(bsum, nb);
    k_scan6_c<<<dim3(nb, 6), 256, 0, stream>>>(rp1, rp2, bsum, nb);
    k_fill6<<<dim3((NEn + 255) / 256, 6), 256, 0, stream>>>(
        ei[0], ei[1], ei[2], ei[0] + NEn, ei[1] + NEn, ei[2] + NEn,
        rp1, rp2, fill1, fill2, el1, el2);

    // ---- weight pre-conversion (after fill6 frees fill1 region) ----
    k_wconv<<<176, 256, 0, stream>>>(Wp, Wl, Wr, Wl2, Wr2, Wp_c, W1_c, W2_c);

    // ---- layer 1 ----
    k_projm3<<<(C2n / 16 + 3) / 4, 256, 0, stream>>>(x, Wp_c, bp, xp3);
    k_gath1<<<dim3(C1n / 16, 3), 256, 0, stream>>>(rp1, el1, xp3, agg3);
    k_out1f<<<(C1n / 16 + 3) / 4, 256, 0, stream>>>(agg3, x, W1_c, bl, g0, b0, h1);

    // ---- layer 2 ----
    k_gath2<<<dim3(C0n / 16, 3), 256, 0, stream>>>(rp2, el2, h1, agg2);
    k_out2f<<<(C0n / 16 + 3) / 4, 256, 0, stream>>>(agg2, h1, W2_c, bl2, g1, b1,
                                                    (float*)d_out);
}

// Round 17
// 590.850 us; speedup vs baseline: 3.4389x; 1.0309x over previous
//
#include <hip/hip_runtime.h>

#define C0n 50000
#define C1n 150000
#define C2n 300000
#define E0n 300000
#define E1n 600000
#define NEn (E0n + E1n)
#define PAD64 76     // 64-col weight tile stride (u16): 152B = 38 words, 38%32=6 -> ~2-way
#define PAD128 140   // 128-col weight tile stride (u16): 280B = 70 words, 70%32=6 -> ~2-way

typedef float  v4f    __attribute__((ext_vector_type(4)));
typedef float  f32x4  __attribute__((ext_vector_type(4)));
typedef short  bf16x8 __attribute__((ext_vector_type(8)));
typedef unsigned short u16;

__device__ __forceinline__ u16 f2bf(float f){
    unsigned u = __builtin_bit_cast(unsigned, f);
    u += 0x7FFFu + ((u >> 16) & 1u);          // RNE
    return (u16)(u >> 16);
}
__device__ __forceinline__ float bf2f(u16 h){
    unsigned u = ((unsigned)h) << 16;
    return __builtin_bit_cast(float, u);
}
__device__ __forceinline__ float bf2f_lo(unsigned u){
    return __builtin_bit_cast(float, u << 16);
}
__device__ __forceinline__ float bf2f_hi(unsigned u){
    return __builtin_bit_cast(float, u & 0xffff0000u);
}
__device__ __forceinline__ f32x4 mfma16(bf16x8 a, bf16x8 b, f32x4 c){
    return __builtin_amdgcn_mfma_f32_16x16x32_bf16(a, b, c, 0, 0, 0);
}
__device__ __forceinline__ float red16(float v){
    v += __shfl_xor(v, 1); v += __shfl_xor(v, 2);
    v += __shfl_xor(v, 4); v += __shfl_xor(v, 8);
    return v;
}
// 8 consecutive f32 -> bf16x8 fragment (16B-aligned source)
__device__ __forceinline__ bf16x8 frag8(const float* __restrict__ p){
    v4f a = *(const v4f*)p, b = *(const v4f*)(p + 4);
    bf16x8 r;
    r[0] = (short)f2bf(a[0]); r[1] = (short)f2bf(a[1]);
    r[2] = (short)f2bf(a[2]); r[3] = (short)f2bf(a[3]);
    r[4] = (short)f2bf(b[0]); r[5] = (short)f2bf(b[1]);
    r[6] = (short)f2bf(b[2]); r[7] = (short)f2bf(b[3]);
    return r;
}

// ------- one-shot: pre-transpose + pre-pad + pre-bf16 all weights into caches -------
__global__ __launch_bounds__(256) void k_wconv(const float* __restrict__ Wp,
    const float* __restrict__ Wl, const float* __restrict__ Wr,
    const float* __restrict__ Wl2, const float* __restrict__ Wr2,
    u16* __restrict__ Wp_c, u16* __restrict__ W1_c, u16* __restrict__ W2_c)
{
    const int i0 = blockIdx.x * 256 + threadIdx.x;
    const int stride = gridDim.x * 256;
    for (int idx = i0; idx < 3 * 64 * PAD64; idx += stride) {
        int t = idx / (64 * PAD64), r = idx % (64 * PAD64);
        int c = r / PAD64, k = r % PAD64;
        Wp_c[idx] = (k < 64) ? f2bf(Wp[t * 4096 + k * 64 + c]) : (u16)0;
    }
    for (int idx = i0; idx < 3 * 128 * PAD128; idx += stride) {
        int t = idx / (128 * PAD128), r = idx % (128 * PAD128);
        int c = r / PAD128, k = r % PAD128;
        u16 v = 0;
        if (k < 64)       v = f2bf(Wl[t * 8192 + k * 128 + c]);
        else if (k < 128) v = f2bf(Wr[t * 8192 + (k - 64) * 128 + c]);
        W1_c[idx] = v;
    }
    for (int idx = i0; idx < 6 * 128 * PAD128; idx += stride) {
        int m = idx / (128 * PAD128), r = idx % (128 * PAD128);
        int t = m % 3;
        const float* W = (m >= 3) ? Wr2 : Wl2;
        int c = r / PAD128, k = r % PAD128;
        W2_c[idx] = (k < 128) ? f2bf(W[t * 16384 + k * 128 + c]) : (u16)0;
    }
}

// ------- xp_t = relu(x @ Wp[t] + bp[t]) for ALL t (r13-validated) -------
__global__ __launch_bounds__(256) void k_projm3(const float* __restrict__ x,
    const u16* __restrict__ Wp_c, const float* __restrict__ bp,
    u16* __restrict__ xp3)
{
    __shared__ __align__(16) u16 Wt[3 * 64 * PAD64];   // 29,184 B
    __shared__ float bps[3 * 64];
    const int tid = threadIdx.x;
    for (int i = tid; i < 192; i += 256) bps[i] = bp[i];
    for (int i = tid; i < 3 * 64 * PAD64 / 8; i += 256)
        ((bf16x8*)Wt)[i] = ((const bf16x8*)Wp_c)[i];
    __syncthreads();

    const int lane = tid & 63, wid = tid >> 6;
    const int lr = lane & 15, lg = lane >> 4;
    const int ntiles = C2n / 16;                  // 18750
    int rt = blockIdx.x * 4 + wid;
    const bool valid = (rt < ntiles);
    if (rt > ntiles - 1) rt = ntiles - 1;         // clamp for loads only
    const int r0 = rt * 16;

    bf16x8 xa[2];
    xa[0] = frag8(&x[(size_t)(r0 + lr) * 64 + 0  + 8 * lg]);
    xa[1] = frag8(&x[(size_t)(r0 + lr) * 64 + 32 + 8 * lg]);

    for (int t = 0; t < 3; t++) {
        f32x4 acc[4];
#pragma unroll
        for (int n = 0; n < 4; n++) acc[n] = 0;
#pragma unroll
        for (int ks = 0; ks < 2; ks++) {
#pragma unroll
            for (int n = 0; n < 4; n++) {
                bf16x8 b = *(const bf16x8*)&Wt[t * 64 * PAD64 + (16 * n + lr) * PAD64 + ks * 32 + 8 * lg];
                acc[n] = mfma16(xa[ks], b, acc[n]);
            }
        }
        if (valid) {
            u16* xp = xp3 + (size_t)t * C2n * 64;
#pragma unroll
            for (int n = 0; n < 4; n++) {
                const float bb = bps[t * 64 + 16 * n + lr];
#pragma unroll
                for (int j = 0; j < 4; j++)
                    xp[(size_t)(r0 + 4 * lg + j) * 64 + 16 * n + lr] =
                        f2bf(fmaxf(acc[n][j] + bb, 0.f));
            }
        }
    }
}

// ================= 6-way CSR build (y<3: layer1 graph y; y>=3: layer2 graph y-3) =================
__global__ __launch_bounds__(256) void k_hist6(const int* __restrict__ d0,
    const int* __restrict__ d1, const int* __restrict__ d2,
    int* __restrict__ rp1, int* __restrict__ rp2)
{
    const int e = blockIdx.x * 256 + threadIdx.x;
    const int y = blockIdx.y;
    const int g = (y < 3) ? y : y - 3;
    const int nE = (y < 3) ? NEn : E0n;
    if (e >= nE) return;
    const int* d = (g == 0) ? d0 : (g == 1) ? d1 : d2;
    int* deg = (y < 3) ? rp1 + (size_t)y * C1n : rp2 + (size_t)(y - 3) * C0n;
    atomicAdd(&deg[d[e]], 1);
}

__global__ __launch_bounds__(256) void k_scan6_a(int* __restrict__ rp1,
    int* __restrict__ rp2, int* __restrict__ bsum, int nblk)
{
    __shared__ int sd[256];
    const int t = threadIdx.x, y = blockIdx.y;
    int* arr = (y < 3) ? rp1 + (size_t)y * C1n : rp2 + (size_t)(y - 3) * C0n;
    const int n = (y < 3) ? C1n : C0n;
    const int base = blockIdx.x * 2048 + t * 8;
    int v[8];
#pragma unroll
    for (int j = 0; j < 8; j++) v[j] = (base + j < n) ? arr[base + j] : 0;
    int tot = 0;
#pragma unroll
    for (int j = 0; j < 8; j++) { int tmp = v[j]; v[j] = tot; tot += tmp; }
    sd[t] = tot; __syncthreads();
    for (int off = 1; off < 256; off <<= 1) {
        int xv = (t >= off) ? sd[t - off] : 0;
        __syncthreads();
        sd[t] += xv;
        __syncthreads();
    }
    const int excl = sd[t] - tot;
#pragma unroll
    for (int j = 0; j < 8; j++)
        if (base + j < n) arr[base + j] = excl + v[j];
    if (t == 255) bsum[y * nblk + blockIdx.x] = sd[255];
}

__global__ __launch_bounds__(256) void k_scan6_b(int* __restrict__ bsum, int nblk)
{
    __shared__ int sd[256];
    const int t = threadIdx.x, y = blockIdx.y;
    int val = (t < nblk) ? bsum[y * nblk + t] : 0;
    sd[t] = val; __syncthreads();
    for (int off = 1; off < 256; off <<= 1) {
        int xv = (t >= off) ? sd[t - off] : 0;
        __syncthreads();
        sd[t] += xv;
        __syncthreads();
    }
    if (t < nblk) bsum[y * nblk + t] = sd[t] - val;
}

__global__ __launch_bounds__(256) void k_scan6_c(int* __restrict__ rp1,
    int* __restrict__ rp2, const int* __restrict__ bsum, int nblk)
{
    const int t = threadIdx.x, y = blockIdx.y;
    int* arr = (y < 3) ? rp1 + (size_t)y * C1n : rp2 + (size_t)(y - 3) * C0n;
    const int n = (y < 3) ? C1n : C0n;
    const int base = blockIdx.x * 2048 + t * 8;
    const int add = bsum[y * nblk + blockIdx.x];
#pragma unroll
    for (int j = 0; j < 8; j++)
        if (base + j < n) arr[base + j] += add;
}

// ------- fill, 8 slice phases: live write-window per phase ~ el/8 -> L2-resident,
//         collapsing the random-scatter cacheline write amplification -------
__global__ __launch_bounds__(256) void k_fill6(const int* __restrict__ s0,
    const int* __restrict__ s1, const int* __restrict__ s2,
    const int* __restrict__ d0, const int* __restrict__ d1, const int* __restrict__ d2,
    const int* __restrict__ rp1, const int* __restrict__ rp2,
    int* __restrict__ fill1, int* __restrict__ fill2,
    int* __restrict__ el1, int* __restrict__ el2)
{
    const int e = blockIdx.x * 256 + threadIdx.x;
    const int y = blockIdx.y;
    const int g = (y < 3) ? y : y - 3;
    const int nE = (y < 3) ? NEn : E0n;
    const int nV = (y < 3) ? C1n : C0n;
    const bool act = (e < nE);

    const int* s = (g == 0) ? s0 : (g == 1) ? s1 : s2;
    const int* d = (g == 0) ? d0 : (g == 1) ? d1 : d2;
    const int* rp  = (y < 3) ? rp1  + (size_t)y * C1n : rp2  + (size_t)(y - 3) * C0n;
    int* fill      = (y < 3) ? fill1 + (size_t)y * C1n : fill2 + (size_t)(y - 3) * C0n;
    int* el        = (y < 3) ? el1  + (size_t)y * NEn : el2  + (size_t)(y - 3) * E0n;

    int dd = 0, ss = 0, mySl = -1;
    if (act) {
        dd = d[e]; ss = s[e];
        mySl = dd / (nV >> 3);                    // nV divisible by 8
    }
    for (int sl = 0; sl < 8; sl++) {
        if (act && sl == mySl) {
            const int pos = rp[dd] + atomicAdd(&fill[dd], 1);
            el[pos] = ss;
        }
        __syncthreads();                          // keep block's threads phase-locked
    }
}

// ------- gather layer1: 16-lane groups (4 rows/wave), 8B/lane loads (r16-validated) -------
__global__ __launch_bounds__(256) void k_gath1(const int* __restrict__ rp1,
    const int* __restrict__ el1, const u16* __restrict__ xp3,
    u16* __restrict__ agg3)
{
    const int t = blockIdx.y;
    const int* rp = rp1 + (size_t)t * C1n;
    const int* el = el1 + (size_t)t * NEn;
    const u16* xp = xp3 + (size_t)t * C2n * 64;
    u16* aggt = agg3 + (size_t)t * C1n * 64;

    const int gid = blockIdx.x * 16 + (threadIdx.x >> 4);   // C1n % 16 == 0
    const int l16 = threadIdx.x & 15;
    const int b = rp[gid];
    const int e = (gid == C1n - 1) ? NEn : rp[gid + 1];

    float s0 = 0.f, s1 = 0.f, s2 = 0.f, s3 = 0.f;
    int i = b;
    for (; i + 1 < e; i += 2) {
        const int sr0 = el[i], sr1 = el[i + 1];
        uint2 u0 = *(const uint2*)&xp[(size_t)sr0 * 64 + l16 * 4];
        uint2 u1 = *(const uint2*)&xp[(size_t)sr1 * 64 + l16 * 4];
        s0 += bf2f_lo(u0.x) + bf2f_lo(u1.x);
        s1 += bf2f_hi(u0.x) + bf2f_hi(u1.x);
        s2 += bf2f_lo(u0.y) + bf2f_lo(u1.y);
        s3 += bf2f_hi(u0.y) + bf2f_hi(u1.y);
    }
    if (i < e) {
        uint2 u = *(const uint2*)&xp[(size_t)el[i] * 64 + l16 * 4];
        s0 += bf2f_lo(u.x); s1 += bf2f_hi(u.x);
        s2 += bf2f_lo(u.y); s3 += bf2f_hi(u.y);
    }
    const float inv = 1.f / (float)max(e - b, 1);
    uint2 o;
    o.x = (unsigned)f2bf(s0 * inv) | ((unsigned)f2bf(s1 * inv) << 16);
    o.y = (unsigned)f2bf(s2 * inv) | ((unsigned)f2bf(s3 * inv) << 16);
    *(uint2*)&aggt[(size_t)gid * 64 + l16 * 4] = o;
}

// ------- fused layer1: staging = vector memcpy from W1_c (r13-validated) -------
__global__ __launch_bounds__(256) void k_out1f(const u16* __restrict__ agg3,
    const float* __restrict__ x, const u16* __restrict__ W1_c,
    const float* __restrict__ bl,
    const float* __restrict__ g0, const float* __restrict__ b0,
    u16* __restrict__ h1)
{
    __shared__ __align__(16) u16 Wt[128 * PAD128];   // 35,840 B
    __shared__ float bls[3 * 128], gs[128], bs[128];
    const int tid = threadIdx.x;
    if (tid < 128) { gs[tid] = g0[tid]; bs[tid] = b0[tid]; }
    for (int i = tid; i < 384; i += 256) bls[i] = bl[i];

    const int lane = tid & 63, wid = tid >> 6;
    const int lr = lane & 15, lg = lane >> 4;
    const int ntiles = C1n / 16;                  // 9375
    int rt = blockIdx.x * 4 + wid;
    const bool valid = (rt < ntiles);
    if (rt > ntiles - 1) rt = ntiles - 1;         // clamp for loads only
    const int r0 = rt * 16;

    bf16x8 xa[2];
    xa[0] = frag8(&x[(size_t)(r0 + lr) * 64 + 0  + 8 * lg]);
    xa[1] = frag8(&x[(size_t)(r0 + lr) * 64 + 32 + 8 * lg]);

    f32x4 hacc[8];
#pragma unroll
    for (int n = 0; n < 8; n++) hacc[n] = 0;

    for (int t = 0; t < 3; t++) {
        __syncthreads();                          // Wt reuse protection
        const bf16x8* src = (const bf16x8*)(W1_c + (size_t)t * 128 * PAD128);
        for (int i = tid; i < 128 * PAD128 / 8; i += 256)
            ((bf16x8*)Wt)[i] = src[i];
        __syncthreads();

        const u16* aggT = agg3 + (size_t)t * C1n * 64;
        f32x4 ta[8];
#pragma unroll
        for (int n = 0; n < 8; n++) ta[n] = 0;
#pragma unroll
        for (int ks = 0; ks < 4; ks++) {
            bf16x8 a;
            if (ks < 2)
                a = *(const bf16x8*)&aggT[(size_t)(r0 + lr) * 64 + ks * 32 + 8 * lg];
            else
                a = xa[ks - 2];
#pragma unroll
            for (int n = 0; n < 8; n++) {
                bf16x8 b = *(const bf16x8*)&Wt[(16 * n + lr) * PAD128 + ks * 32 + 8 * lg];
                ta[n] = mfma16(a, b, ta[n]);
            }
        }
        float ss[4] = {0.f, 0.f, 0.f, 0.f};
#pragma unroll
        for (int n = 0; n < 8; n++) {
            const float bb = bls[t * 128 + 16 * n + lr];
#pragma unroll
            for (int j = 0; j < 4; j++) {
                ta[n][j] += bb;
                ss[j] += ta[n][j] * ta[n][j];
            }
        }
#pragma unroll
        for (int j = 0; j < 4; j++)
            ss[j] = 1.f / fmaxf(sqrtf(red16(ss[j])), 1e-12f);
#pragma unroll
        for (int n = 0; n < 8; n++)
#pragma unroll
            for (int j = 0; j < 4; j++) hacc[n][j] += ta[n][j] * ss[j];
    }

    float mu[4] = {0.f, 0.f, 0.f, 0.f};
#pragma unroll
    for (int n = 0; n < 8; n++)
#pragma unroll
        for (int j = 0; j < 4; j++) {
            float v = fmaxf(hacc[n][j], 0.f) * (1.f / 3.f);
            hacc[n][j] = v; mu[j] += v;
        }
#pragma unroll
    for (int j = 0; j < 4; j++) mu[j] = red16(mu[j]) * (1.f / 128.f);
    float var[4] = {0.f, 0.f, 0.f, 0.f};
#pragma unroll
    for (int n = 0; n < 8; n++)
#pragma unroll
        for (int j = 0; j < 4; j++) {
            float d = hacc[n][j] - mu[j]; var[j] += d * d;
        }
#pragma unroll
    for (int j = 0; j < 4; j++) var[j] = rsqrtf(red16(var[j]) * (1.f / 128.f) + 1e-5f);

    if (valid) {
#pragma unroll
        for (int n = 0; n < 8; n++) {
            const float g = gs[16 * n + lr], bb = bs[16 * n + lr];
#pragma unroll
            for (int j = 0; j < 4; j++) {
                float o = (hacc[n][j] - mu[j]) * var[j] * g + bb;
                h1[(size_t)(r0 + 4 * lg + j) * 128 + 16 * n + lr] = f2bf(o);
            }
        }
    }
}

// ------- gather layer2: 16-lane groups, 16B/lane loads (r16-validated) -------
__global__ __launch_bounds__(256) void k_gath2(const int* __restrict__ rp2,
    const int* __restrict__ el2, const u16* __restrict__ h1,
    u16* __restrict__ agg2)
{
    const int t = blockIdx.y;
    const int* rp = rp2 + (size_t)t * C0n;
    const int* el = el2 + (size_t)t * E0n;
    u16* agg2t = agg2 + (size_t)t * C0n * 128;

    const int gid = blockIdx.x * 16 + (threadIdx.x >> 4);   // C0n % 16 == 0
    const int l16 = threadIdx.x & 15;
    const int b = rp[gid];
    const int e = (gid == C0n - 1) ? E0n : rp[gid + 1];

    float s[8];
#pragma unroll
    for (int j = 0; j < 8; j++) s[j] = 0.f;
    int i = b;
    for (; i + 1 < e; i += 2) {
        const int sr0 = el[i], sr1 = el[i + 1];
        uint4 u0 = *(const uint4*)&h1[(size_t)sr0 * 128 + l16 * 8];
        uint4 u1 = *(const uint4*)&h1[(size_t)sr1 * 128 + l16 * 8];
        s[0] += bf2f_lo(u0.x) + bf2f_lo(u1.x);
        s[1] += bf2f_hi(u0.x) + bf2f_hi(u1.x);
        s[2] += bf2f_lo(u0.y) + bf2f_lo(u1.y);
        s[3] += bf2f_hi(u0.y) + bf2f_hi(u1.y);
        s[4] += bf2f_lo(u0.z) + bf2f_lo(u1.z);
        s[5] += bf2f_hi(u0.z) + bf2f_hi(u1.z);
        s[6] += bf2f_lo(u0.w) + bf2f_lo(u1.w);
        s[7] += bf2f_hi(u0.w) + bf2f_hi(u1.w);
    }
    if (i < e) {
        uint4 u = *(const uint4*)&h1[(size_t)el[i] * 128 + l16 * 8];
        s[0] += bf2f_lo(u.x); s[1] += bf2f_hi(u.x);
        s[2] += bf2f_lo(u.y); s[3] += bf2f_hi(u.y);
        s[4] += bf2f_lo(u.z); s[5] += bf2f_hi(u.z);
        s[6] += bf2f_lo(u.w); s[7] += bf2f_hi(u.w);
    }
    const float inv = 1.f / (float)max(e - b, 1);
    uint4 o;
    o.x = (unsigned)f2bf(s[0] * inv) | ((unsigned)f2bf(s[1] * inv) << 16);
    o.y = (unsigned)f2bf(s[2] * inv) | ((unsigned)f2bf(s[3] * inv) << 16);
    o.z = (unsigned)f2bf(s[4] * inv) | ((unsigned)f2bf(s[5] * inv) << 16);
    o.w = (unsigned)f2bf(s[6] * inv) | ((unsigned)f2bf(s[7] * inv) << 16);
    *(uint4*)&agg2t[(size_t)gid * 128 + l16 * 8] = o;
}

// ------- fused layer2: staging = vector memcpy from W2_c (r13-validated) -------
__global__ __launch_bounds__(256) void k_out2f(const u16* __restrict__ agg2,
    const u16* __restrict__ h1, const u16* __restrict__ W2_c,
    const float* __restrict__ bl2,
    const float* __restrict__ g1, const float* __restrict__ b1,
    float* __restrict__ out)
{
    __shared__ __align__(16) u16 Wt[128 * PAD128];
    __shared__ float bsm[128], gs[128], bs[128];
    const int tid = threadIdx.x;
    if (tid < 128) {
        gs[tid] = g1[tid]; bs[tid] = b1[tid];
        bsm[tid] = bl2[tid] + bl2[128 + tid] + bl2[256 + tid];
    }
    const int lane = tid & 63, wid = tid >> 6;
    const int lr = lane & 15, lg = lane >> 4;
    const int ntiles = C0n / 16;                  // 3125
    int rt = blockIdx.x * 4 + wid;
    const bool valid = (rt < ntiles);
    if (rt > ntiles - 1) rt = ntiles - 1;         // clamp for loads only
    const int r0 = rt * 16;

    bf16x8 ha[4];
#pragma unroll
    for (int ks = 0; ks < 4; ks++)
        ha[ks] = *(const bf16x8*)&h1[(size_t)(r0 + lr) * 128 + ks * 32 + 8 * lg];

    f32x4 acc[8];
#pragma unroll
    for (int n = 0; n < 8; n++) acc[n] = 0;

    for (int t = 0; t < 3; t++) {
        for (int hh = 0; hh < 2; hh++) {
            __syncthreads();                      // Wt reuse protection
            const bf16x8* src = (const bf16x8*)(W2_c +
                (size_t)((hh ? 3 : 0) + t) * 128 * PAD128);
            for (int i = tid; i < 128 * PAD128 / 8; i += 256)
                ((bf16x8*)Wt)[i] = src[i];
            __syncthreads();
#pragma unroll
            for (int ks = 0; ks < 4; ks++) {
                bf16x8 a;
                if (hh == 0)
                    a = *(const bf16x8*)&agg2[(size_t)t * C0n * 128 +
                                              (size_t)(r0 + lr) * 128 + ks * 32 + 8 * lg];
                else
                    a = ha[ks];
#pragma unroll
                for (int n = 0; n < 8; n++) {
                    bf16x8 b = *(const bf16x8*)&Wt[(16 * n + lr) * PAD128 + ks * 32 + 8 * lg];
                    acc[n] = mfma16(a, b, acc[n]);
                }
            }
        }
    }

    float mu[4] = {0.f, 0.f, 0.f, 0.f};
#pragma unroll
    for (int n = 0; n < 8; n++) {
        const float bb = bsm[16 * n + lr];
#pragma unroll
        for (int j = 0; j < 4; j++) {
            float v = fmaxf((acc[n][j] + bb) * (1.f / 3.f), 0.f);
            acc[n][j] = v; mu[j] += v;
        }
    }
#pragma unroll
    for (int j = 0; j < 4; j++) mu[j] = red16(mu[j]) * (1.f / 128.f);
    float var[4] = {0.f, 0.f, 0.f, 0.f};
#pragma unroll
    for (int n = 0; n < 8; n++)
#pragma unroll
        for (int j = 0; j < 4; j++) {
            float d = acc[n][j] - mu[j]; var[j] += d * d;
        }
#pragma unroll
    for (int j = 0; j < 4; j++) var[j] = rsqrtf(red16(var[j]) * (1.f / 128.f) + 1e-5f);

    if (valid) {
#pragma unroll
        for (int n = 0; n < 8; n++) {
            const float g = gs[16 * n + lr], bb = bs[16 * n + lr];
#pragma unroll
            for (int j = 0; j < 4; j++) {
                float o = (acc[n][j] - mu[j]) * var[j] * g + bb;
                out[(size_t)(r0 + 4 * lg + j) * 128 + 16 * n + lr] = o;
            }
        }
    }
}

extern "C" void kernel_launch(void* const* d_in, const int* in_sizes, int n_in,
                              void* d_out, int out_size, void* d_ws, size_t ws_size,
                              hipStream_t stream)
{
    const float* x   = (const float*)d_in[0];
    const int*   ei[3] = { (const int*)d_in[1], (const int*)d_in[2], (const int*)d_in[3] };
    const float* Wp  = (const float*)d_in[6];
    const float* bp  = (const float*)d_in[7];
    const float* Wl  = (const float*)d_in[8];
    const float* bl  = (const float*)d_in[9];
    const float* Wr  = (const float*)d_in[10];
    const float* Wl2 = (const float*)d_in[11];
    const float* bl2 = (const float*)d_in[12];
    const float* Wr2 = (const float*)d_in[13];
    const float* g0  = (const float*)d_in[14];
    const float* b0  = (const float*)d_in[15];
    const float* g1  = (const float*)d_in[16];
    const float* b1  = (const float*)d_in[17];

    // ---- workspace layout (bytes) ----
    char* W = (char*)d_ws;
    u16*   agg3 = (u16*)(W + 0);             // 3*C1*64 bf16 = 57,600,000
    u16*   xp3  = (u16*)(W + 57600000);      // 3*C2*64 bf16 = 115,200,000 -> 172,800,000
    u16*   h1   = (u16*)(W + 57600000);      // C1*128 bf16 = 38,400,000 (overlays xp3 t=0)
    int*   rp1  = (int*)(W + 172800000);     // 3*C1*4 = 1,800,000
    int*   fill1= (int*)(W + 174600000);     // 1,800,000 (dead after fill6)
    int*   bsum = (int*)(W + 176400000);     // 4 KiB (6*74*4 = 1776 B used)
    int*   el1  = (int*)(W + 176404096);     // 3*NE*4 = 10,800,000 -> 187,204,096
    int*   rp2  = (int*)(W + 187204096);     // 3*C0*4 = 600,000
    int*   fill2= (int*)(W + 187804096);     // 600,000
    int*   el2  = (int*)(W + 188404096);     // 3*E0*4 = 3,600,000 -> ends 192,004,096
    // weight caches overlay fill1 (dead after fill6); total 351,744 B < 1.8MB
    u16*   Wp_c = (u16*)(W + 174600000);     // 29,184
    u16*   W1_c = (u16*)(W + 174629184);     // 107,520
    u16*   W2_c = (u16*)(W + 174736704);     // 215,040 -> ends 174,951,744
    // layer-2 overlays: agg3 dead after out1f
    u16*   agg2 = (u16*)(W + 0);             // 3*C0*128 bf16 = 38,400,000

    const int nb = (C1n + 2047) / 2048;  // 74 (covers C0n too; excess blocks no-op)

    // ---- both layers' CSR in 6-way merged kernels ----
    hipMemsetAsync(rp1, 0, 2 * 3 * (size_t)C1n * 4, stream);   // rp1 + fill1
    hipMemsetAsync(rp2, 0, 2 * 3 * (size_t)C0n * 4, stream);   // rp2 + fill2
    k_hist6<<<dim3((NEn + 255) / 256, 6), 256, 0, stream>>>(
        ei[0] + NEn, ei[1] + NEn, ei[2] + NEn, rp1, rp2);
    k_scan6_a<<<dim3(nb, 6), 256, 0, stream>>>(rp1, rp2, bsum, nb);
    k_scan6_b<<<dim3(1, 6), 256, 0, stream>>>(bsum, nb);
    k_scan6_c<<<dim3(nb, 6), 256, 0, stream>>>(rp1, rp2, bsum, nb);
    k_fill6<<<dim3((NEn + 255) / 256, 6), 256, 0, stream>>>(
        ei[0], ei[1], ei[2], ei[0] + NEn, ei[1] + NEn, ei[2] + NEn,
        rp1, rp2, fill1, fill2, el1, el2);

    // ---- weight pre-conversion (after fill6 frees fill1 region) ----
    k_wconv<<<176, 256, 0, stream>>>(Wp, Wl, Wr, Wl2, Wr2, Wp_c, W1_c, W2_c);

    // ---- layer 1 ----
    k_projm3<<<(C2n / 16 + 3) / 4, 256, 0, stream>>>(x, Wp_c, bp, xp3);
    k_gath1<<<dim3(C1n / 16, 3), 256, 0, stream>>>(rp1, el1, xp3, agg3);
    k_out1f<<<(C1n / 16 + 3) / 4, 256, 0, stream>>>(agg3, x, W1_c, bl, g0, b0, h1);

    // ---- layer 2 ----
    k_gath2<<<dim3(C0n / 16, 3), 256, 0, stream>>>(rp2, el2, h1, agg2);
    k_out2f<<<(C0n / 16 + 3) / 4, 256, 0, stream>>>(agg2, h1, W2_c, bl2, g1, b1,
                                                    (float*)d_out);
}